// Round 7
// baseline (179.006 us; speedup 1.0000x reference)
//
#include <hip/hip_runtime.h>
#include <hip/hip_bf16.h>
#include <stdint.h>

typedef unsigned short u16;
typedef __attribute__((ext_vector_type(8))) __bf16 bf16x8;
typedef __attribute__((ext_vector_type(2))) __bf16 bf16x2;
typedef __attribute__((ext_vector_type(4))) float f32x4;
typedef __attribute__((ext_vector_type(4))) u16 u16x4;
typedef __attribute__((ext_vector_type(4))) float f32x4v;

typedef __attribute__((address_space(1))) void gvoid_t;
typedef __attribute__((address_space(3))) void lvoid_t;

#define BAR()     asm volatile("s_barrier" ::: "memory")
#define WAITV4()  asm volatile("s_waitcnt vmcnt(4)" ::: "memory")
#define WAITV8()  asm volatile("s_waitcnt vmcnt(8)" ::: "memory")
#define WAITV12() asm volatile("s_waitcnt vmcnt(12)" ::: "memory")
#define WAITV16() asm volatile("s_waitcnt vmcnt(16)" ::: "memory")
#define WAITV0()  asm volatile("s_waitcnt vmcnt(0)" ::: "memory")

__device__ inline u16 f2bf(float f) {
    uint32_t u = __float_as_uint(f);
    u += 0x7fff + ((u >> 16) & 1);   // RNE
    return (u16)(u >> 16);
}

__device__ inline void gll16(const void* g, void* l) {
    __builtin_amdgcn_global_load_lds((gvoid_t*)g, (lvoid_t*)l, 16, 0, 0);
}

__device__ inline f32x4 mfma16(bf16x8 a, bf16x8 b, f32x4 c) {
    return __builtin_amdgcn_mfma_f32_16x16x32_bf16(a, b, c, 0, 0, 0);
}

// V slot permutation: context row r (mod 64) -> storage slot, so that the PV
// A-fragment is IN-LANE after swapped QK^T (keys n*16+g*4+j live in lane g).
__device__ inline int vslot(int r) {
    int n = r >> 4;
    return ((n >> 1) << 5) + (((r >> 2) & 3) << 3) + ((n & 1) << 2) + (r & 3);
}

// ---------------- cast fp32 -> bf16 (vectorized) ----------------
__global__ __launch_bounds__(256) void cast_bf16_kernel(
        const float* __restrict__ in, u16* __restrict__ out, int n4) {
    int i = blockIdx.x * 256 + threadIdx.x;
    if (i >= n4) return;
    f32x4v f = ((const f32x4v*)in)[i];
    u16x4 o;
    o[0] = f2bf(f[0]); o[1] = f2bf(f[1]); o[2] = f2bf(f[2]); o[3] = f2bf(f[3]);
    ((u16x4*)out)[i] = o;
}

// ---------------- transpose + cast: W[K][N] fp32 -> WT[N][K] bf16 ----------------
__global__ __launch_bounds__(256) void trans_cast_kernel(
        const float* __restrict__ W, u16* __restrict__ WT, int K, int N) {
    __shared__ float t[32][33];
    int x = threadIdx.x;           // 0..31
    int y = threadIdx.y;           // 0..7
    int n0 = blockIdx.x * 32;
    int k0 = blockIdx.y * 32;
    for (int yy = y; yy < 32; yy += 8)
        t[yy][x] = W[(size_t)(k0 + yy) * N + n0 + x];
    __syncthreads();
    for (int yy = y; yy < 32; yy += 8)
        WT[(size_t)(n0 + yy) * K + k0 + x] = f2bf(t[x][yy]);
}

// ---------------- small GEMM (128x128 tile): C = A @ Bt^T ----------------
// MODE 0: out0 = bf16[M][N], value=(acc+bias)*scale     (Q proj)
// MODE 2: out0 = fp32 [M][N]                            (O proj -> d_out)
template <int MODE>
__global__ __launch_bounds__(256) void gemm_bt(
        const u16* __restrict__ A, const u16* __restrict__ Bt,
        const float* __restrict__ bias, int M, int N, int K,
        float scale, void* __restrict__ out0, u16* __restrict__ out1) {
    __shared__ u16 lA[2][128 * 32];
    __shared__ u16 lB[2][128 * 32];
    const int tid = threadIdx.x;
    const int lane = tid & 63, wv = tid >> 6;
    const int c16 = lane & 15, g = lane >> 4;
    const int m0 = blockIdx.y * 128, n0 = blockIdx.x * 128;
    const int wm = (wv >> 1) * 64, wn = (wv & 1) * 64;

    const int i0 = tid, i1 = tid + 256;
    const int r0 = i0 >> 2, cc0 = (i0 & 3) ^ ((r0 >> 1) & 3);
    const int r1 = i1 >> 2, cc1 = (i1 & 3) ^ ((r1 >> 1) & 3);
    const int dst0 = (wv * 64) * 8;
    const int dst1 = (256 + wv * 64) * 8;

    auto stage = [&](int buf, int k0) {
        gll16(A + (size_t)(m0 + r0) * K + k0 + cc0 * 8, &lA[buf][dst0]);
        gll16(A + (size_t)(m0 + r1) * K + k0 + cc1 * 8, &lA[buf][dst1]);
        gll16(Bt + (size_t)(n0 + r0) * K + k0 + cc0 * 8, &lB[buf][dst0]);
        gll16(Bt + (size_t)(n0 + r1) * K + k0 + cc1 * 8, &lB[buf][dst1]);
    };

    f32x4 acc[4][4] = {};
    stage(0, 0);
    __syncthreads();
    int buf = 0;
    for (int k0 = 0; k0 < K; k0 += 32) {
        if (k0 + 32 < K) stage(buf ^ 1, k0 + 32);
        bf16x8 af[4], bfr[4];
#pragma unroll
        for (int m = 0; m < 4; m++) {
            int row = wm + m * 16 + c16;
            af[m] = *(const bf16x8*)&lA[buf][row * 32 + (g ^ ((row >> 1) & 3)) * 8];
        }
#pragma unroll
        for (int n = 0; n < 4; n++) {
            int row = wn + n * 16 + c16;
            bfr[n] = *(const bf16x8*)&lB[buf][row * 32 + (g ^ ((row >> 1) & 3)) * 8];
        }
#pragma unroll
        for (int m = 0; m < 4; m++)
#pragma unroll
            for (int n = 0; n < 4; n++)
                acc[m][n] = mfma16(af[m], bfr[n], acc[m][n]);
        __syncthreads();
        buf ^= 1;
    }

#pragma unroll
    for (int n = 0; n < 4; n++) {
        int col = n0 + wn + n * 16 + c16;
        float bv = bias[col];
#pragma unroll
        for (int m = 0; m < 4; m++) {
            int rowb = m0 + wm + m * 16 + g * 4;
#pragma unroll
            for (int j = 0; j < 4; j++) {
                float v = (acc[m][n][j] + bv) * scale;
                int row = rowb + j;
                if (MODE == 0) {
                    ((u16*)out0)[(size_t)row * N + col] = f2bf(v);
                } else {
                    ((float*)out0)[(size_t)row * N + col] = v;
                }
            }
        }
    }
}

// ---------------- big GEMM: 256x256, 8 waves, A-only 4-slot ring, B direct ------
// KV projection: C[8192][2048] = A @ Bt^T + bias. B-fragments read straight from
// L2 (WkvT is 4MB, L2-resident) -> LDS traffic/tile drops 128KB -> 80KB and LDS
// shrinks to 64KB. A staged via gll16 ring (4 slots x 16KB), counted vmcnt.
// Body t issues: [stage A(t+3): 2 gll16] then [B(t): 4 global b128] (in compute).
// after-A(t) counts: t=0:4, t=1:8, t=2:12, steady:16, tail:12.
__global__ __launch_bounds__(512, 2) void gemm_kv_ring(
        const u16* __restrict__ A, const u16* __restrict__ Bt,
        const float* __restrict__ bias, u16* __restrict__ Kp,
        u16* __restrict__ VpT) {
    __shared__ u16 lds[4][256 * 32];      // A ring: 4 slots x 16KB = 64KB
    const int K = 1024, NT = 32;          // K / 32
    const int tid = threadIdx.x;
    const int lane = tid & 63, wv = tid >> 6;
    const int c16 = lane & 15, g = lane >> 4;

    // T1: XCD-aware swizzle (grid 8x32=256, %8==0 -> simple bijective form)
    const int nwg = gridDim.x * gridDim.y;
    const int bid = blockIdx.y * gridDim.x + blockIdx.x;
    const int cpx = nwg >> 3;
    const int sw = (bid & 7) * cpx + (bid >> 3);
    const int bx = sw % gridDim.x, by = sw / gridDim.x;
    const int m0 = by * 256, n0 = bx * 256;

    // A staging: all 8 waves, 2 gll16 each; chunk i -> row i>>2, swz pos i&3
    const int i0 = tid, i1 = tid + 512;
    const int r0 = i0 >> 2, cc0 = (i0 & 3) ^ ((r0 >> 1) & 3);
    const int r1 = i1 >> 2, cc1 = (i1 & 3) ^ ((r1 >> 1) & 3);
    const size_t offA0 = (size_t)(m0 + r0) * K + cc0 * 8;
    const size_t offA1 = (size_t)(m0 + r1) * K + cc1 * 8;
    const int dst0 = (wv * 64) * 8;
    const int dst1 = (512 + wv * 64) * 8;

    auto stage = [&](int t) {
        u16* d = &lds[t & 3][0];
        gll16(A + offA0 + t * 32, d + dst0);
        gll16(A + offA1 + t * 32, d + dst1);
    };

    const int wm = wv >> 2;        // 0..1 -> 128-row half
    const int wn = wv & 3;         // 0..3 -> 64-col quarter
    // per-lane B base: col = n0 + wn*64 + n*16 + c16 (frag n at +n*16*K), k-chunk g
    const u16* bp = Bt + (size_t)(n0 + wn * 64 + c16) * K + g * 8;

    f32x4 acc[8][4] = {};

    auto compute = [&](int t) {
        const u16* la = &lds[t & 3][0];
        bf16x8 bfr[4], af[8];
#pragma unroll
        for (int n = 0; n < 4; n++)
            bfr[n] = *(const bf16x8*)(bp + (size_t)n * 16 * K + t * 32);
#pragma unroll
        for (int m = 0; m < 8; m++) {
            int row = wm * 128 + m * 16 + c16;
            af[m] = *(const bf16x8*)&la[row * 32 + (g ^ ((row >> 1) & 3)) * 8];
        }
        __builtin_amdgcn_s_setprio(1);
#pragma unroll
        for (int m = 0; m < 8; m++)
#pragma unroll
            for (int n = 0; n < 4; n++)
                acc[m][n] = mfma16(af[m], bfr[n], acc[m][n]);
        __builtin_amdgcn_s_setprio(0);
    };

    // prologue: tiles 0,1,2 -> slots 0,1,2 (6 gll16/wave in flight)
    stage(0); stage(1); stage(2);

    for (int t = 0; t < NT; ++t) {
        if (t == 0)      WAITV4();
        else if (t == 1) WAITV8();
        else if (t == 2 || t >= NT - 2) WAITV12();
        else             WAITV16();
        BAR();
        if (t + 3 < NT) stage(t + 3);
        compute(t);
    }

    const bool isV = (n0 >= 1024);
#pragma unroll
    for (int n = 0; n < 4; n++) {
        int col = n0 + wn * 64 + n * 16 + c16;
        float bv = bias[col];
#pragma unroll
        for (int m = 0; m < 8; m++) {
            int rowb = m0 + wm * 128 + m * 16 + g * 4;
            if (isV) {
                u16x4 pk;
#pragma unroll
                for (int j = 0; j < 4; j++) pk[j] = f2bf(acc[m][n][j] + bv);
                int vcol = (rowb & ~63) + vslot(rowb & 63);
                *(u16x4*)&VpT[(size_t)(col - 1024) * 8192 + vcol] = pk;
            } else {
#pragma unroll
                for (int j = 0; j < 4; j++)
                    Kp[(size_t)(rowb + j) * 1024 + col] = f2bf(acc[m][n][j] + bv);
            }
        }
    }
}

// ---------------- flash attention, kv-split x2, in-lane-P softmax ----------------
__global__ __launch_bounds__(256, 5) void attn_split_kernel(
        const u16* __restrict__ Qp, const u16* __restrict__ Kp,
        const u16* __restrict__ VpT, float* __restrict__ Opart,
        float* __restrict__ ml) {
    __shared__ u16 lKV[2][2][64 * 64];   // [slot][K=0/V=1]  = 32768 B
    const int NT = 16;
    const int tid = threadIdx.x;
    const int lane = tid & 63, wv = tid >> 6;
    const int c16 = lane & 15, g = lane >> 4;
    const int bid = blockIdx.x;
    const int qblk = bid >> 7;            // high bits -> same XCD for all qblk
    const int low = bid & 127;
    const int h = low & 15, z = low >> 4;
    const int b = z >> 1, sp = z & 1;
    const int kvbase = sp * 1024;

    const int qrow = b * 512 + qblk * 64 + wv * 16 + c16;
    bf16x8 qf[2];
    qf[0] = *(const bf16x8*)(Qp + (size_t)qrow * 1024 + h * 64 + g * 8);
    qf[1] = *(const bf16x8*)(Qp + (size_t)qrow * 1024 + h * 64 + 32 + g * 8);

    f32x4 acc[4] = {};
    float m_s = -1e30f, l_s = 0.f;       // q = c16, log2 domain

    const int i0 = tid, i1 = tid + 256;
    const int r0 = i0 >> 3, c0 = (i0 & 7) ^ (r0 & 7);
    const int r1 = i1 >> 3, c1 = (i1 & 7) ^ (r1 & 7);
    const int dst0 = (wv * 64) * 8, dst1 = (256 + wv * 64) * 8;

    auto stageKV = [&](int buf, int t) {
        int kv0 = kvbase + t * 64;
        u16* dK = &lKV[buf][0][0];
        u16* dV = &lKV[buf][1][0];
        gll16(Kp + (size_t)(b * 2048 + kv0 + r0) * 1024 + h * 64 + c0 * 8, dK + dst0);
        gll16(Kp + (size_t)(b * 2048 + kv0 + r1) * 1024 + h * 64 + c1 * 8, dK + dst1);
        gll16(VpT + (size_t)(h * 64 + r0) * 8192 + b * 2048 + kv0 + c0 * 8, dV + dst0);
        gll16(VpT + (size_t)(h * 64 + r1) * 8192 + b * 2048 + kv0 + c1 * 8, dV + dst1);
    };

    stageKV(0, 0);
    int buf = 0;
    for (int t = 0; t < NT; ++t) {
        __syncthreads();                  // tile t landed; buf^1 free
        if (t + 1 < NT) stageKV(buf ^ 1, t + 1);

        const u16* lK = &lKV[buf][0][0];
        const u16* lV = &lKV[buf][1][0];

        // S^T = K Q^T : s[n][j] = S2[q=c16][key = n*16 + g*4 + j]
        f32x4 s[4];
#pragma unroll
        for (int n = 0; n < 4; n++) {
            s[n] = f32x4{0.f, 0.f, 0.f, 0.f};
            int key = n * 16 + c16;
#pragma unroll
            for (int kk = 0; kk < 2; kk++) {
                bf16x8 kf = *(const bf16x8*)&lK[key * 64 + (((kk * 4 + g) ^ (key & 7))) * 8];
                s[n] = mfma16(kf, qf[kk], s[n]);
            }
        }

        // tree max for q=c16 (+2 shuffles across g groups)
        float mn0 = fmaxf(fmaxf(s[0][0], s[0][1]), fmaxf(s[0][2], s[0][3]));
        float mn1 = fmaxf(fmaxf(s[1][0], s[1][1]), fmaxf(s[1][2], s[1][3]));
        float mn2 = fmaxf(fmaxf(s[2][0], s[2][1]), fmaxf(s[2][2], s[2][3]));
        float mn3 = fmaxf(fmaxf(s[3][0], s[3][1]), fmaxf(s[3][2], s[3][3]));
        float mx = fmaxf(fmaxf(mn0, mn1), fmaxf(mn2, mn3));
        mx = fmaxf(mx, __shfl_xor(mx, 16));
        mx = fmaxf(mx, __shfl_xor(mx, 32));

        // defer-max: rescale only when some row grew by > 8 (log2 domain)
        if (!__all(mx - m_s <= 8.0f)) {
            float mn = fmaxf(m_s, mx);
            float al = exp2f(m_s - mn);
            m_s = mn;
            l_s *= al;
            float alr[4];
#pragma unroll
            for (int j = 0; j < 4; j++) alr[j] = __shfl(al, g * 4 + j);
#pragma unroll
            for (int nd = 0; nd < 4; nd++)
#pragma unroll
                for (int j = 0; j < 4; j++) acc[nd][j] *= alr[j];
        }

        // P = exp2(S2 - m), packed to bf16 pairs in-register
        uint32_t r[4][2];
        float sums[4];
#pragma unroll
        for (int n = 0; n < 4; n++) {
            float p0 = exp2f(s[n][0] - m_s);
            float p1 = exp2f(s[n][1] - m_s);
            float p2 = exp2f(s[n][2] - m_s);
            float p3 = exp2f(s[n][3] - m_s);
            sums[n] = (p0 + p1) + (p2 + p3);
            union { bf16x2 h; uint32_t u; } ca, cb;
            ca.h[0] = (__bf16)p0; ca.h[1] = (__bf16)p1;
            cb.h[0] = (__bf16)p2; cb.h[1] = (__bf16)p3;
            r[n][0] = ca.u; r[n][1] = cb.u;
        }
        float sum = (sums[0] + sums[1]) + (sums[2] + sums[3]);
        sum += __shfl_xor(sum, 16);
        sum += __shfl_xor(sum, 32);
        l_s += sum;

        // O += P @ V : A-fragment fully IN-LANE (VpT columns stored in vslot order)
#pragma unroll
        for (int kk2 = 0; kk2 < 2; kk2++) {
            union { bf16x8 v8; uint32_t u[4]; } pa;
            pa.u[0] = r[kk2 * 2][0];
            pa.u[1] = r[kk2 * 2][1];
            pa.u[2] = r[kk2 * 2 + 1][0];
            pa.u[3] = r[kk2 * 2 + 1][1];
#pragma unroll
            for (int nd = 0; nd < 4; nd++) {
                int d = nd * 16 + c16;
                bf16x8 vf = *(const bf16x8*)&lV[d * 64 + (((kk2 * 4 + g) ^ (d & 7))) * 8];
                acc[nd] = mfma16(pa.v8, vf, acc[nd]);
            }
        }
        buf ^= 1;
    }

    // write partials: unnormalized O (rows g*4+j) + per-row m,l (g==0 lanes, row c16)
#pragma unroll
    for (int j = 0; j < 4; j++) {
        int rowq = b * 512 + qblk * 64 + wv * 16 + g * 4 + j;
        size_t idx = (size_t)sp * 32768 + (size_t)rowq * 16 + h;
#pragma unroll
        for (int nd = 0; nd < 4; nd++)
            Opart[idx * 64 + nd * 16 + c16] = acc[nd][j];
    }
    if (g == 0) {
        int rowq = b * 512 + qblk * 64 + wv * 16 + c16;
        size_t idx = (size_t)sp * 32768 + (size_t)rowq * 16 + h;
        ml[idx * 2] = m_s;
        ml[idx * 2 + 1] = l_s;
    }
}

// ---------------- combine the 2 kv-split partials -> X bf16 (log2-domain m) ------
__global__ __launch_bounds__(256) void attn_combine_kernel(
        const float* __restrict__ Opart, const float* __restrict__ ml,
        u16* __restrict__ X) {
    const int tid = threadIdx.x;
    const int r = blockIdx.x * 4 + (tid >> 6);   // rowhead 0..32767
    const int d = tid & 63;
    float m0 = ml[(size_t)r * 2], l0 = ml[(size_t)r * 2 + 1];
    float m1 = ml[(size_t)(32768 + r) * 2], l1 = ml[(size_t)(32768 + r) * 2 + 1];
    float M = fmaxf(m0, m1);
    float a0 = exp2f(m0 - M), a1 = exp2f(m1 - M);
    float li = 1.f / (l0 * a0 + l1 * a1);
    float o0 = Opart[(size_t)r * 64 + d];
    float o1 = Opart[(size_t)(32768 + r) * 64 + d];
    float o = (o0 * a0 + o1 * a1) * li;
    int qrow = r >> 4, h = r & 15;
    X[(size_t)qrow * 1024 + h * 64 + d] = f2bf(o);
}

// ---------------- launch ----------------
extern "C" void kernel_launch(void* const* d_in, const int* in_sizes, int n_in,
                              void* d_out, int out_size, void* d_ws, size_t ws_size,
                              hipStream_t stream) {
    const float* queries = (const float*)d_in[0];   // [4,512,1024]
    const float* context = (const float*)d_in[1];   // [4,2048,1024]
    const float* Wq      = (const float*)d_in[2];   // [1024,1024]
    const float* bq      = (const float*)d_in[3];   // [1024]
    const float* Wkv     = (const float*)d_in[4];   // [1024,2048]
    const float* bkv     = (const float*)d_in[5];   // [2048]
    const float* Wo      = (const float*)d_in[6];   // [1024,1024]
    const float* bo      = (const float*)d_in[7];   // [1024]

    char* ws = (char*)d_ws;
    u16* qb   = (u16*)(ws);                         // queries bf16   4MB (dead after Q-proj)
    u16* cb   = (u16*)(ws + (4ull  << 20));         // context bf16  16MB (dead after KV GEMM)
    u16* WqT  = (u16*)(ws + (20ull << 20));         // Wq^T bf16      2MB
    u16* WkvT = (u16*)(ws + (22ull << 20));         // Wkv^T bf16     4MB
    u16* WoT  = (u16*)(ws + (26ull << 20));         // Wo^T bf16      2MB
    u16* Qp   = (u16*)(ws + (28ull << 20));         // q proj (x0.125*log2e) 4MB
    u16* Kp   = (u16*)(ws + (32ull << 20));         // k proj        16MB
    u16* VpT  = (u16*)(ws + (48ull << 20));         // v proj ^T (vslot cols) 16MB
    u16* X    = (u16*)(ws + (64ull << 20));         // attn out       4MB
    float* ml    = (float*)qb;                      // 1MB, aliases dead qb
    float* Opart = (float*)cb;                      // 16MB, aliases dead cb

    cast_bf16_kernel<<<dim3(2048), dim3(256), 0, stream>>>(queries, qb, 524288);
    cast_bf16_kernel<<<dim3(8192), dim3(256), 0, stream>>>(context, cb, 2097152);
    trans_cast_kernel<<<dim3(32, 32), dim3(32, 8), 0, stream>>>(Wq, WqT, 1024, 1024);
    trans_cast_kernel<<<dim3(64, 32), dim3(32, 8), 0, stream>>>(Wkv, WkvT, 1024, 2048);
    trans_cast_kernel<<<dim3(32, 32), dim3(32, 8), 0, stream>>>(Wo, WoT, 1024, 1024);

    // scale = 1/8 * log2(e): scores computed directly in exp2 domain
    gemm_bt<0><<<dim3(8, 16), dim3(256), 0, stream>>>(qb, WqT, bq, 2048, 1024, 1024,
                                                      0.18033688f, (void*)Qp, (u16*)nullptr);
    gemm_kv_ring<<<dim3(8, 32), dim3(512), 0, stream>>>(cb, WkvT, bkv, Kp, VpT);
    attn_split_kernel<<<dim3(1024), dim3(256), 0, stream>>>(Qp, Kp, VpT, Opart, ml);
    attn_combine_kernel<<<dim3(8192), dim3(256), 0, stream>>>(Opart, ml, X);
    gemm_bt<2><<<dim3(8, 16), dim3(256), 0, stream>>>(X, WoT, bo, 2048, 1024, 1024,
                                                      1.0f, d_out, (u16*)nullptr);
}

// Round 8
// 152.651 us; speedup vs baseline: 1.1726x; 1.1726x over previous
//
#include <hip/hip_runtime.h>
#include <hip/hip_bf16.h>
#include <stdint.h>

typedef unsigned short u16;
typedef __attribute__((ext_vector_type(8))) __bf16 bf16x8;
typedef __attribute__((ext_vector_type(2))) __bf16 bf16x2;
typedef __attribute__((ext_vector_type(4))) float f32x4;
typedef __attribute__((ext_vector_type(4))) u16 u16x4;
typedef __attribute__((ext_vector_type(4))) float f32x4v;

typedef __attribute__((address_space(1))) void gvoid_t;
typedef __attribute__((address_space(3))) void lvoid_t;

#define BAR()    asm volatile("s_barrier" ::: "memory")
#define WAITV0() asm volatile("s_waitcnt vmcnt(0)" ::: "memory")
#define WAITV2() asm volatile("s_waitcnt vmcnt(2)" ::: "memory")
#define WAITV4() asm volatile("s_waitcnt vmcnt(4)" ::: "memory")
#define WAITV8() asm volatile("s_waitcnt vmcnt(8)" ::: "memory")

__device__ inline u16 f2bf(float f) {
    uint32_t u = __float_as_uint(f);
    u += 0x7fff + ((u >> 16) & 1);   // RNE
    return (u16)(u >> 16);
}

__device__ inline void gll16(const void* g, void* l) {
    __builtin_amdgcn_global_load_lds((gvoid_t*)g, (lvoid_t*)l, 16, 0, 0);
}

__device__ inline f32x4 mfma16(bf16x8 a, bf16x8 b, f32x4 c) {
    return __builtin_amdgcn_mfma_f32_16x16x32_bf16(a, b, c, 0, 0, 0);
}

// V slot permutation: context row r (mod 64) -> storage slot, so that the PV
// A-fragment is IN-LANE after swapped QK^T (keys n*16+g*4+j live in lane g).
__device__ inline int vslot(int r) {
    int n = r >> 4;
    return ((n >> 1) << 5) + (((r >> 2) & 3) << 3) + ((n & 1) << 2) + (r & 3);
}

// ---------------- cast fp32 -> bf16 (vectorized) ----------------
__global__ __launch_bounds__(256) void cast_bf16_kernel(
        const float* __restrict__ in, u16* __restrict__ out, int n4) {
    int i = blockIdx.x * 256 + threadIdx.x;
    if (i >= n4) return;
    f32x4v f = ((const f32x4v*)in)[i];
    u16x4 o;
    o[0] = f2bf(f[0]); o[1] = f2bf(f[1]); o[2] = f2bf(f[2]); o[3] = f2bf(f[3]);
    ((u16x4*)out)[i] = o;
}

// ---------------- transpose + cast: W[K][N] fp32 -> WT[N][K] bf16 ----------------
__global__ __launch_bounds__(256) void trans_cast_kernel(
        const float* __restrict__ W, u16* __restrict__ WT, int K, int N) {
    __shared__ float t[32][33];
    int x = threadIdx.x;           // 0..31
    int y = threadIdx.y;           // 0..7
    int n0 = blockIdx.x * 32;
    int k0 = blockIdx.y * 32;
    for (int yy = y; yy < 32; yy += 8)
        t[yy][x] = W[(size_t)(k0 + yy) * N + n0 + x];
    __syncthreads();
    for (int yy = y; yy < 32; yy += 8)
        WT[(size_t)(n0 + yy) * K + k0 + x] = f2bf(t[x][yy]);
}

// ---------------- small GEMM (128x128 tile): C = A @ Bt^T ----------------
// MODE 0: out0 = bf16[M][N], value=(acc+bias)*scale     (Q proj)
// MODE 2: out0 = fp32 [M][N]                            (O proj -> d_out)
template <int MODE>
__global__ __launch_bounds__(256) void gemm_bt(
        const u16* __restrict__ A, const u16* __restrict__ Bt,
        const float* __restrict__ bias, int M, int N, int K,
        float scale, void* __restrict__ out0, u16* __restrict__ out1) {
    __shared__ u16 lA[2][128 * 32];
    __shared__ u16 lB[2][128 * 32];
    const int tid = threadIdx.x;
    const int lane = tid & 63, wv = tid >> 6;
    const int c16 = lane & 15, g = lane >> 4;
    const int m0 = blockIdx.y * 128, n0 = blockIdx.x * 128;
    const int wm = (wv >> 1) * 64, wn = (wv & 1) * 64;

    const int i0 = tid, i1 = tid + 256;
    const int r0 = i0 >> 2, cc0 = (i0 & 3) ^ ((r0 >> 1) & 3);
    const int r1 = i1 >> 2, cc1 = (i1 & 3) ^ ((r1 >> 1) & 3);
    const int dst0 = (wv * 64) * 8;
    const int dst1 = (256 + wv * 64) * 8;

    auto stage = [&](int buf, int k0) {
        gll16(A + (size_t)(m0 + r0) * K + k0 + cc0 * 8, &lA[buf][dst0]);
        gll16(A + (size_t)(m0 + r1) * K + k0 + cc1 * 8, &lA[buf][dst1]);
        gll16(Bt + (size_t)(n0 + r0) * K + k0 + cc0 * 8, &lB[buf][dst0]);
        gll16(Bt + (size_t)(n0 + r1) * K + k0 + cc1 * 8, &lB[buf][dst1]);
    };

    f32x4 acc[4][4] = {};
    stage(0, 0);
    __syncthreads();
    int buf = 0;
    for (int k0 = 0; k0 < K; k0 += 32) {
        if (k0 + 32 < K) stage(buf ^ 1, k0 + 32);
        bf16x8 af[4], bfr[4];
#pragma unroll
        for (int m = 0; m < 4; m++) {
            int row = wm + m * 16 + c16;
            af[m] = *(const bf16x8*)&lA[buf][row * 32 + (g ^ ((row >> 1) & 3)) * 8];
        }
#pragma unroll
        for (int n = 0; n < 4; n++) {
            int row = wn + n * 16 + c16;
            bfr[n] = *(const bf16x8*)&lB[buf][row * 32 + (g ^ ((row >> 1) & 3)) * 8];
        }
#pragma unroll
        for (int m = 0; m < 4; m++)
#pragma unroll
            for (int n = 0; n < 4; n++)
                acc[m][n] = mfma16(af[m], bfr[n], acc[m][n]);
        __syncthreads();
        buf ^= 1;
    }

#pragma unroll
    for (int n = 0; n < 4; n++) {
        int col = n0 + wn + n * 16 + c16;
        float bv = bias[col];
#pragma unroll
        for (int m = 0; m < 4; m++) {
            int rowb = m0 + wm + m * 16 + g * 4;
#pragma unroll
            for (int j = 0; j < 4; j++) {
                float v = (acc[m][n][j] + bv) * scale;
                int row = rowb + j;
                if (MODE == 0) {
                    ((u16*)out0)[(size_t)row * N + col] = f2bf(v);
                } else {
                    ((float*)out0)[(size_t)row * N + col] = v;
                }
            }
        }
    }
}

// ---------------- big GEMM: 256x256 tile, 8 waves, 4-deep ring, counted vmcnt ----
// (R6-proven version: A and B both staged via gll16 ring; 44 us, 0 conflicts)
// V output stored column-permuted per 64-block (vslot) for in-lane attn PV.
__global__ __launch_bounds__(512, 2) void gemm_kv_ring(
        const u16* __restrict__ A, const u16* __restrict__ Bt,
        const float* __restrict__ bias, u16* __restrict__ Kp,
        u16* __restrict__ VpT) {
    __shared__ u16 lds[4][2][256 * 32];   // [slot][A=0/B=1][row*32 + swz-chunk*8]
    const int K = 1024, NT = 32;          // K / 32
    const int tid = threadIdx.x;
    const int lane = tid & 63, wv = tid >> 6;
    const int c16 = lane & 15, g = lane >> 4;

    // T1: XCD-aware swizzle (grid 8x32=256, %8==0 -> simple bijective form)
    const int nwg = gridDim.x * gridDim.y;
    const int bid = blockIdx.y * gridDim.x + blockIdx.x;
    const int cpx = nwg >> 3;
    const int sw = (bid & 7) * cpx + (bid >> 3);
    const int bx = sw % gridDim.x, by = sw / gridDim.x;
    const int m0 = by * 256, n0 = bx * 256;

    const int isB = wv >> 2;
    const int rbase = (wv & 3) * 64;
    const u16* src = isB ? Bt : A;
    const int base0 = isB ? n0 : m0;
    size_t off[4];
    const u16* ldst[4];
#pragma unroll
    for (int i = 0; i < 4; i++) {
        int rl = rbase + i * 16 + (lane >> 2);
        int ch = (lane & 3) ^ ((rl >> 1) & 3);
        off[i] = (size_t)(base0 + rl) * K + ch * 8;
        ldst[i] = &lds[0][0][0] + ((size_t)isB * 256 * 32) + (size_t)(rbase + i * 16) * 32;
    }
    const size_t slotStride = 2 * 256 * 32;

    auto stage = [&](int t) {
        const u16* s0 = src + (size_t)t * 32;
        u16* d = (u16*)ldst[0] + (size_t)(t & 3) * slotStride;
        gll16(s0 + off[0], d);
        gll16(s0 + off[1], d + 16 * 32);
        gll16(s0 + off[2], d + 32 * 32);
        gll16(s0 + off[3], d + 48 * 32);
    };

    const int wm = wv >> 2;
    const int wn = wv & 3;
    f32x4 acc[8][4] = {};

    auto compute = [&](int slot) {
        const u16* la = &lds[slot][0][0];
        const u16* lb = &lds[slot][1][0];
        bf16x8 af[8], bfr[4];
#pragma unroll
        for (int m = 0; m < 8; m++) {
            int row = wm * 128 + m * 16 + c16;
            af[m] = *(const bf16x8*)&la[row * 32 + (g ^ ((row >> 1) & 3)) * 8];
        }
#pragma unroll
        for (int n = 0; n < 4; n++) {
            int row = wn * 64 + n * 16 + c16;
            bfr[n] = *(const bf16x8*)&lb[row * 32 + (g ^ ((row >> 1) & 3)) * 8];
        }
#pragma unroll
        for (int m = 0; m < 8; m++)
#pragma unroll
            for (int n = 0; n < 4; n++)
                acc[m][n] = mfma16(af[m], bfr[n], acc[m][n]);
    };

    stage(0); stage(1); stage(2);

    for (int t = 0; t < NT - 2; ++t) {
        WAITV8();
        BAR();
        if (t + 3 < NT) stage(t + 3);
        compute(t & 3);
    }
    WAITV4(); BAR(); compute((NT - 2) & 3);
    WAITV0(); BAR(); compute((NT - 1) & 3);

    const bool isV = (n0 >= 1024);
#pragma unroll
    for (int n = 0; n < 4; n++) {
        int col = n0 + wn * 64 + n * 16 + c16;
        float bv = bias[col];
#pragma unroll
        for (int m = 0; m < 8; m++) {
            int rowb = m0 + wm * 128 + m * 16 + g * 4;
            if (isV) {
                u16x4 pk;
#pragma unroll
                for (int j = 0; j < 4; j++) pk[j] = f2bf(acc[m][n][j] + bv);
                int vcol = (rowb & ~63) + vslot(rowb & 63);
                *(u16x4*)&VpT[(size_t)(col - 1024) * 8192 + vcol] = pk;
            } else {
#pragma unroll
                for (int j = 0; j < 4; j++)
                    Kp[(size_t)(rowb + j) * 1024 + col] = f2bf(acc[m][n][j] + bv);
            }
        }
    }
}

// ---------------- flash attention: QBLK=128, 8 waves, 3-slot counted ring -------
// grid 512 (1-D): qblk(2b) in HIGH bits -> the 4 KV-sharing blocks + same-slab
// (h,b,sp) blocks group per XCD (bid mod 128 fixed => bid mod 8 fixed).
// Per wave: 16 q-rows (q=c16), 16 kv tiles of 64 keys; 8 waves SHARE each staged
// tile (halves staging traffic + barriers/work vs 4-wave). 3-slot ring + counted
// vmcnt(2): prefetch 2 tiles ahead, never drained mid-loop (T4). LDS 48KB ->
// 2 blocks/CU co-resident (launch_bounds(512,4)).
__global__ __launch_bounds__(512, 4) void attn_split_kernel(
        const u16* __restrict__ Qp, const u16* __restrict__ Kp,
        const u16* __restrict__ VpT, float* __restrict__ Opart,
        float* __restrict__ ml) {
    __shared__ u16 lKV[3][2][64 * 64];   // [slot][K=0/V=1] = 49152 B
    const int NT = 16;
    const int tid = threadIdx.x;
    const int lane = tid & 63, wv = tid >> 6;      // wv 0..7
    const int c16 = lane & 15, g = lane >> 4;
    const int bid = blockIdx.x;
    const int qblk = bid >> 7;            // 0..3, high bits
    const int low = bid & 127;
    const int h = low & 15, z = low >> 4;
    const int b = z >> 1, sp = z & 1;
    const int kvbase = sp * 1024;

    const int qrow = b * 512 + qblk * 128 + wv * 16 + c16;
    bf16x8 qf[2];
    qf[0] = *(const bf16x8*)(Qp + (size_t)qrow * 1024 + h * 64 + g * 8);
    qf[1] = *(const bf16x8*)(Qp + (size_t)qrow * 1024 + h * 64 + 32 + g * 8);

    f32x4 acc[4] = {};
    float m_s = -1e30f, l_s = 0.f;       // q = c16, log2 domain

    // staging: 512 threads cover one 64x64 tile per matrix; entry tid ->
    // row r0=tid>>3, stored pos tid&7 holds source chunk c0=(tid&7)^(r0&7);
    // linear LDS offset = tid*8 u16 -> wave-uniform base wv*512, lane*16B by HW
    const int r0 = tid >> 3, c0 = (tid & 7) ^ (r0 & 7);
    const int dstw = wv * 512;           // u16 offset

    auto stageKV = [&](int t) {
        int slot = t % 3;
        int kv0 = kvbase + t * 64;
        u16* dK = &lKV[slot][0][0];
        u16* dV = &lKV[slot][1][0];
        gll16(Kp + (size_t)(b * 2048 + kv0 + r0) * 1024 + h * 64 + c0 * 8, dK + dstw);
        gll16(VpT + (size_t)(h * 64 + r0) * 8192 + b * 2048 + kv0 + c0 * 8, dV + dstw);
    };

    stageKV(0); stageKV(1);
    for (int t = 0; t < NT; ++t) {
        if (t < NT - 2) { WAITV2(); } else { WAITV0(); }
        BAR();
        if (t + 2 < NT) stageKV(t + 2);

        const int slot = t % 3;
        const u16* lK = &lKV[slot][0][0];
        const u16* lV = &lKV[slot][1][0];

        // S^T = K Q^T : s[n][j] = S2[q=c16][key = n*16 + g*4 + j]
        f32x4 s[4];
#pragma unroll
        for (int n = 0; n < 4; n++) {
            s[n] = f32x4{0.f, 0.f, 0.f, 0.f};
            int key = n * 16 + c16;
#pragma unroll
            for (int kk = 0; kk < 2; kk++) {
                bf16x8 kf = *(const bf16x8*)&lK[key * 64 + (((kk * 4 + g) ^ (key & 7))) * 8];
                s[n] = mfma16(kf, qf[kk], s[n]);
            }
        }

        // tree max for q=c16 (+2 shuffles across g groups)
        float mn0 = fmaxf(fmaxf(s[0][0], s[0][1]), fmaxf(s[0][2], s[0][3]));
        float mn1 = fmaxf(fmaxf(s[1][0], s[1][1]), fmaxf(s[1][2], s[1][3]));
        float mn2 = fmaxf(fmaxf(s[2][0], s[2][1]), fmaxf(s[2][2], s[2][3]));
        float mn3 = fmaxf(fmaxf(s[3][0], s[3][1]), fmaxf(s[3][2], s[3][3]));
        float mx = fmaxf(fmaxf(mn0, mn1), fmaxf(mn2, mn3));
        mx = fmaxf(mx, __shfl_xor(mx, 16));
        mx = fmaxf(mx, __shfl_xor(mx, 32));

        // defer-max: rescale only when some row grew by > 8 (log2 domain)
        if (!__all(mx - m_s <= 8.0f)) {
            float mn = fmaxf(m_s, mx);
            float al = exp2f(m_s - mn);
            m_s = mn;
            l_s *= al;
            float alr[4];
#pragma unroll
            for (int j = 0; j < 4; j++) alr[j] = __shfl(al, g * 4 + j);
#pragma unroll
            for (int nd = 0; nd < 4; nd++)
#pragma unroll
                for (int j = 0; j < 4; j++) acc[nd][j] *= alr[j];
        }

        // P = exp2(S2 - m), packed to bf16 pairs in-register
        uint32_t r[4][2];
        float sums[4];
#pragma unroll
        for (int n = 0; n < 4; n++) {
            float p0 = exp2f(s[n][0] - m_s);
            float p1 = exp2f(s[n][1] - m_s);
            float p2 = exp2f(s[n][2] - m_s);
            float p3 = exp2f(s[n][3] - m_s);
            sums[n] = (p0 + p1) + (p2 + p3);
            union { bf16x2 h; uint32_t u; } ca, cb;
            ca.h[0] = (__bf16)p0; ca.h[1] = (__bf16)p1;
            cb.h[0] = (__bf16)p2; cb.h[1] = (__bf16)p3;
            r[n][0] = ca.u; r[n][1] = cb.u;
        }
        float sum = (sums[0] + sums[1]) + (sums[2] + sums[3]);
        sum += __shfl_xor(sum, 16);
        sum += __shfl_xor(sum, 32);
        l_s += sum;

        // O += P @ V : A-fragment fully IN-LANE (VpT columns stored in vslot order)
#pragma unroll
        for (int kk2 = 0; kk2 < 2; kk2++) {
            union { bf16x8 v8; uint32_t u[4]; } pa;
            pa.u[0] = r[kk2 * 2][0];
            pa.u[1] = r[kk2 * 2][1];
            pa.u[2] = r[kk2 * 2 + 1][0];
            pa.u[3] = r[kk2 * 2 + 1][1];
#pragma unroll
            for (int nd = 0; nd < 4; nd++) {
                int d = nd * 16 + c16;
                bf16x8 vf = *(const bf16x8*)&lV[d * 64 + (((kk2 * 4 + g) ^ (d & 7))) * 8];
                acc[nd] = mfma16(pa.v8, vf, acc[nd]);
            }
        }
    }

    // write partials: unnormalized O (rows g*4+j) + per-row m,l (g==0 lanes, row c16)
#pragma unroll
    for (int j = 0; j < 4; j++) {
        int rowq = b * 512 + qblk * 128 + wv * 16 + g * 4 + j;
        size_t idx = (size_t)sp * 32768 + (size_t)rowq * 16 + h;
#pragma unroll
        for (int nd = 0; nd < 4; nd++)
            Opart[idx * 64 + nd * 16 + c16] = acc[nd][j];
    }
    if (g == 0) {
        int rowq = b * 512 + qblk * 128 + wv * 16 + c16;
        size_t idx = (size_t)sp * 32768 + (size_t)rowq * 16 + h;
        ml[idx * 2] = m_s;
        ml[idx * 2 + 1] = l_s;
    }
}

// ---------------- combine the 2 kv-split partials -> X bf16 (log2-domain m) ------
__global__ __launch_bounds__(256) void attn_combine_kernel(
        const float* __restrict__ Opart, const float* __restrict__ ml,
        u16* __restrict__ X) {
    const int tid = threadIdx.x;
    const int r = blockIdx.x * 4 + (tid >> 6);   // rowhead 0..32767
    const int d = tid & 63;
    float m0 = ml[(size_t)r * 2], l0 = ml[(size_t)r * 2 + 1];
    float m1 = ml[(size_t)(32768 + r) * 2], l1 = ml[(size_t)(32768 + r) * 2 + 1];
    float M = fmaxf(m0, m1);
    float a0 = exp2f(m0 - M), a1 = exp2f(m1 - M);
    float li = 1.f / (l0 * a0 + l1 * a1);
    float o0 = Opart[(size_t)r * 64 + d];
    float o1 = Opart[(size_t)(32768 + r) * 64 + d];
    float o = (o0 * a0 + o1 * a1) * li;
    int qrow = r >> 4, h = r & 15;
    X[(size_t)qrow * 1024 + h * 64 + d] = f2bf(o);
}

// ---------------- launch ----------------
extern "C" void kernel_launch(void* const* d_in, const int* in_sizes, int n_in,
                              void* d_out, int out_size, void* d_ws, size_t ws_size,
                              hipStream_t stream) {
    const float* queries = (const float*)d_in[0];   // [4,512,1024]
    const float* context = (const float*)d_in[1];   // [4,2048,1024]
    const float* Wq      = (const float*)d_in[2];   // [1024,1024]
    const float* bq      = (const float*)d_in[3];   // [1024]
    const float* Wkv     = (const float*)d_in[4];   // [1024,2048]
    const float* bkv     = (const float*)d_in[5];   // [2048]
    const float* Wo      = (const float*)d_in[6];   // [1024,1024]
    const float* bo      = (const float*)d_in[7];   // [1024]

    char* ws = (char*)d_ws;
    u16* qb   = (u16*)(ws);                         // queries bf16   4MB (dead after Q-proj)
    u16* cb   = (u16*)(ws + (4ull  << 20));         // context bf16  16MB (dead after KV GEMM)
    u16* WqT  = (u16*)(ws + (20ull << 20));         // Wq^T bf16      2MB
    u16* WkvT = (u16*)(ws + (22ull << 20));         // Wkv^T bf16     4MB
    u16* WoT  = (u16*)(ws + (26ull << 20));         // Wo^T bf16      2MB
    u16* Qp   = (u16*)(ws + (28ull << 20));         // q proj (x0.125*log2e) 4MB
    u16* Kp   = (u16*)(ws + (32ull << 20));         // k proj        16MB
    u16* VpT  = (u16*)(ws + (48ull << 20));         // v proj ^T (vslot cols) 16MB
    u16* X    = (u16*)(ws + (64ull << 20));         // attn out       4MB
    float* ml    = (float*)qb;                      // 1MB, aliases dead qb
    float* Opart = (float*)cb;                      // 16MB, aliases dead cb

    cast_bf16_kernel<<<dim3(2048), dim3(256), 0, stream>>>(queries, qb, 524288);
    cast_bf16_kernel<<<dim3(8192), dim3(256), 0, stream>>>(context, cb, 2097152);
    trans_cast_kernel<<<dim3(32, 32), dim3(32, 8), 0, stream>>>(Wq, WqT, 1024, 1024);
    trans_cast_kernel<<<dim3(64, 32), dim3(32, 8), 0, stream>>>(Wkv, WkvT, 1024, 2048);
    trans_cast_kernel<<<dim3(32, 32), dim3(32, 8), 0, stream>>>(Wo, WoT, 1024, 1024);

    // scale = 1/8 * log2(e): scores computed directly in exp2 domain
    gemm_bt<0><<<dim3(8, 16), dim3(256), 0, stream>>>(qb, WqT, bq, 2048, 1024, 1024,
                                                      0.18033688f, (void*)Qp, (u16*)nullptr);
    gemm_kv_ring<<<dim3(8, 32), dim3(512), 0, stream>>>(cb, WkvT, bkv, Kp, VpT);
    attn_split_kernel<<<dim3(512), dim3(512), 0, stream>>>(Qp, Kp, VpT, Opart, ml);
    attn_combine_kernel<<<dim3(8192), dim3(256), 0, stream>>>(Opart, ml, X);
    gemm_bt<2><<<dim3(8, 16), dim3(256), 0, stream>>>(X, WoT, bo, 2048, 1024, 1024,
                                                      1.0f, d_out, (u16*)nullptr);
}

// Round 9
// 131.552 us; speedup vs baseline: 1.3607x; 1.1604x over previous
//
#include <hip/hip_runtime.h>
#include <hip/hip_bf16.h>
#include <stdint.h>

typedef unsigned short u16;
typedef __attribute__((ext_vector_type(8))) __bf16 bf16x8;
typedef __attribute__((ext_vector_type(2))) __bf16 bf16x2;
typedef __attribute__((ext_vector_type(4))) float f32x4;
typedef __attribute__((ext_vector_type(4))) u16 u16x4;
typedef __attribute__((ext_vector_type(4))) float f32x4v;

typedef __attribute__((address_space(1))) void gvoid_t;
typedef __attribute__((address_space(3))) void lvoid_t;

#define BAR()    asm volatile("s_barrier" ::: "memory")
#define WAITV0() asm volatile("s_waitcnt vmcnt(0)" ::: "memory")
#define WAITV2() asm volatile("s_waitcnt vmcnt(2)" ::: "memory")
#define WAITV4() asm volatile("s_waitcnt vmcnt(4)" ::: "memory")
#define WAITV8() asm volatile("s_waitcnt vmcnt(8)" ::: "memory")

__device__ inline u16 f2bf(float f) {
    uint32_t u = __float_as_uint(f);
    u += 0x7fff + ((u >> 16) & 1);   // RNE
    return (u16)(u >> 16);
}

__device__ inline float bf2f(u16 v) {
    return __uint_as_float(((uint32_t)v) << 16);
}

__device__ inline void gll16(const void* g, void* l) {
    __builtin_amdgcn_global_load_lds((gvoid_t*)g, (lvoid_t*)l, 16, 0, 0);
}

__device__ inline f32x4 mfma16(bf16x8 a, bf16x8 b, f32x4 c) {
    return __builtin_amdgcn_mfma_f32_16x16x32_bf16(a, b, c, 0, 0, 0);
}

// V slot permutation: context row r (mod 64) -> storage slot, so that the PV
// A-fragment is IN-LANE after swapped QK^T (keys n*16+g*4+j live in lane g).
__device__ inline int vslot(int r) {
    int n = r >> 4;
    return ((n >> 1) << 5) + (((r >> 2) & 3) << 3) + ((n & 1) << 2) + (r & 3);
}

// ---------------- cast fp32 -> bf16 (vectorized) ----------------
__global__ __launch_bounds__(256) void cast_bf16_kernel(
        const float* __restrict__ in, u16* __restrict__ out, int n4) {
    int i = blockIdx.x * 256 + threadIdx.x;
    if (i >= n4) return;
    f32x4v f = ((const f32x4v*)in)[i];
    u16x4 o;
    o[0] = f2bf(f[0]); o[1] = f2bf(f[1]); o[2] = f2bf(f[2]); o[3] = f2bf(f[3]);
    ((u16x4*)out)[i] = o;
}

// ---------------- transpose + cast: W[K][N] fp32 -> WT[N][K] bf16 ----------------
__global__ __launch_bounds__(256) void trans_cast_kernel(
        const float* __restrict__ W, u16* __restrict__ WT, int K, int N) {
    __shared__ float t[32][33];
    int x = threadIdx.x;           // 0..31
    int y = threadIdx.y;           // 0..7
    int n0 = blockIdx.x * 32;
    int k0 = blockIdx.y * 32;
    for (int yy = y; yy < 32; yy += 8)
        t[yy][x] = W[(size_t)(k0 + yy) * N + n0 + x];
    __syncthreads();
    for (int yy = y; yy < 32; yy += 8)
        WT[(size_t)(n0 + yy) * K + k0 + x] = f2bf(t[x][yy]);
}

// ---------------- small GEMM: 128x128 tile, 8 waves, 4-slot counted ring --------
// (schedule clone of the proven gemm_kv_ring: prologue 3 tiles, steady vmcnt(4))
// MODE 0: out0 = bf16[M][N], value=(acc+bias)*scale     (Q proj)
// MODE 2: out0 = fp32 [M][N]                            (O proj -> d_out)
template <int MODE>
__global__ __launch_bounds__(512, 2) void gemm_bt(
        const u16* __restrict__ A, const u16* __restrict__ Bt,
        const float* __restrict__ bias, int M, int N, int K,
        float scale, void* __restrict__ out0) {
    __shared__ u16 lds[4][2][128 * 32];   // 4 slots x (A,B) x 8KB = 64KB
    const int NT = K >> 5;                // K/32
    const int tid = threadIdx.x;          // 0..511
    const int lane = tid & 63, wv = tid >> 6;   // wv 0..7
    const int c16 = lane & 15, g = lane >> 4;
    const int m0 = blockIdx.y * 128, n0 = blockIdx.x * 128;

    // staging: tile = 512 chunks of 16B; thread tid covers chunk tid of A and of B.
    // row r0 = tid>>2, stored pos tid&3 holds source chunk (tid&3)^((r0>>1)&3).
    const int r0 = tid >> 2, cc0 = (tid & 3) ^ ((r0 >> 1) & 3);
    const size_t offA = (size_t)(m0 + r0) * K + cc0 * 8;
    const size_t offB = (size_t)(n0 + r0) * K + cc0 * 8;
    const int dstw = wv * 512;            // wave-uniform u16 base (lane*16B by HW)

    auto stage = [&](int t) {
        gll16(A + offA + t * 32, &lds[t & 3][0][0] + dstw);
        gll16(Bt + offB + t * 32, &lds[t & 3][1][0] + dstw);
    };

    // per-wave output: rows (wv>>1)*32 .. +31, cols (wv&1)*64 .. +63
    const int wm = (wv >> 1) * 32, wn = (wv & 1) * 64;
    f32x4 acc[2][4] = {};

    auto compute = [&](int slot) {
        const u16* la = &lds[slot][0][0];
        const u16* lb = &lds[slot][1][0];
        bf16x8 af[2], bfr[4];
#pragma unroll
        for (int m = 0; m < 2; m++) {
            int row = wm + m * 16 + c16;
            af[m] = *(const bf16x8*)&la[row * 32 + (g ^ ((row >> 1) & 3)) * 8];
        }
#pragma unroll
        for (int n = 0; n < 4; n++) {
            int row = wn + n * 16 + c16;
            bfr[n] = *(const bf16x8*)&lb[row * 32 + (g ^ ((row >> 1) & 3)) * 8];
        }
#pragma unroll
        for (int m = 0; m < 2; m++)
#pragma unroll
            for (int n = 0; n < 4; n++)
                acc[m][n] = mfma16(af[m], bfr[n], acc[m][n]);
    };

    stage(0); stage(1); stage(2);        // 6 loads/wave in flight

    for (int t = 0; t < NT - 2; ++t) {
        WAITV4();                        // tile t landed; t+1,t+2 (4 loads) in flight
        BAR();
        if (t + 3 < NT) stage(t + 3);    // slot (t+3)&3, freed by barrier
        compute(t & 3);
    }
    WAITV2(); BAR(); compute((NT - 2) & 3);
    WAITV0(); BAR(); compute((NT - 1) & 3);

#pragma unroll
    for (int n = 0; n < 4; n++) {
        int col = n0 + wn + n * 16 + c16;
        float bv = bias[col];
#pragma unroll
        for (int m = 0; m < 2; m++) {
            int rowb = m0 + wm + m * 16 + g * 4;
#pragma unroll
            for (int j = 0; j < 4; j++) {
                float v = (acc[m][n][j] + bv) * scale;
                int row = rowb + j;
                if (MODE == 0) {
                    ((u16*)out0)[(size_t)row * N + col] = f2bf(v);
                } else {
                    ((float*)out0)[(size_t)row * N + col] = v;
                }
            }
        }
    }
}

// ---------------- big GEMM: 256x256 tile, 8 waves, 4-deep ring, counted vmcnt ----
// (R6-proven version; 44 us, 0 conflicts)
// V output stored column-permuted per 64-block (vslot) for in-lane attn PV.
__global__ __launch_bounds__(512, 2) void gemm_kv_ring(
        const u16* __restrict__ A, const u16* __restrict__ Bt,
        const float* __restrict__ bias, u16* __restrict__ Kp,
        u16* __restrict__ VpT) {
    __shared__ u16 lds[4][2][256 * 32];   // [slot][A=0/B=1][row*32 + swz-chunk*8]
    const int K = 1024, NT = 32;          // K / 32
    const int tid = threadIdx.x;
    const int lane = tid & 63, wv = tid >> 6;
    const int c16 = lane & 15, g = lane >> 4;

    // T1: XCD-aware swizzle (grid 8x32=256, %8==0 -> simple bijective form)
    const int nwg = gridDim.x * gridDim.y;
    const int bid = blockIdx.y * gridDim.x + blockIdx.x;
    const int cpx = nwg >> 3;
    const int sw = (bid & 7) * cpx + (bid >> 3);
    const int bx = sw % gridDim.x, by = sw / gridDim.x;
    const int m0 = by * 256, n0 = bx * 256;

    const int isB = wv >> 2;
    const int rbase = (wv & 3) * 64;
    const u16* src = isB ? Bt : A;
    const int base0 = isB ? n0 : m0;
    size_t off[4];
    const u16* ldst[4];
#pragma unroll
    for (int i = 0; i < 4; i++) {
        int rl = rbase + i * 16 + (lane >> 2);
        int ch = (lane & 3) ^ ((rl >> 1) & 3);
        off[i] = (size_t)(base0 + rl) * K + ch * 8;
        ldst[i] = &lds[0][0][0] + ((size_t)isB * 256 * 32) + (size_t)(rbase + i * 16) * 32;
    }
    const size_t slotStride = 2 * 256 * 32;

    auto stage = [&](int t) {
        const u16* s0 = src + (size_t)t * 32;
        u16* d = (u16*)ldst[0] + (size_t)(t & 3) * slotStride;
        gll16(s0 + off[0], d);
        gll16(s0 + off[1], d + 16 * 32);
        gll16(s0 + off[2], d + 32 * 32);
        gll16(s0 + off[3], d + 48 * 32);
    };

    const int wm = wv >> 2;
    const int wn = wv & 3;
    f32x4 acc[8][4] = {};

    auto compute = [&](int slot) {
        const u16* la = &lds[slot][0][0];
        const u16* lb = &lds[slot][1][0];
        bf16x8 af[8], bfr[4];
#pragma unroll
        for (int m = 0; m < 8; m++) {
            int row = wm * 128 + m * 16 + c16;
            af[m] = *(const bf16x8*)&la[row * 32 + (g ^ ((row >> 1) & 3)) * 8];
        }
#pragma unroll
        for (int n = 0; n < 4; n++) {
            int row = wn * 64 + n * 16 + c16;
            bfr[n] = *(const bf16x8*)&lb[row * 32 + (g ^ ((row >> 1) & 3)) * 8];
        }
#pragma unroll
        for (int m = 0; m < 8; m++)
#pragma unroll
            for (int n = 0; n < 4; n++)
                acc[m][n] = mfma16(af[m], bfr[n], acc[m][n]);
    };

    stage(0); stage(1); stage(2);

    for (int t = 0; t < NT - 2; ++t) {
        WAITV8();
        BAR();
        if (t + 3 < NT) stage(t + 3);
        compute(t & 3);
    }
    WAITV4(); BAR(); compute((NT - 2) & 3);
    WAITV0(); BAR(); compute((NT - 1) & 3);

    const bool isV = (n0 >= 1024);
#pragma unroll
    for (int n = 0; n < 4; n++) {
        int col = n0 + wn * 64 + n * 16 + c16;
        float bv = bias[col];
#pragma unroll
        for (int m = 0; m < 8; m++) {
            int rowb = m0 + wm * 128 + m * 16 + g * 4;
            if (isV) {
                u16x4 pk;
#pragma unroll
                for (int j = 0; j < 4; j++) pk[j] = f2bf(acc[m][n][j] + bv);
                int vcol = (rowb & ~63) + vslot(rowb & 63);
                *(u16x4*)&VpT[(size_t)(col - 1024) * 8192 + vcol] = pk;
            } else {
#pragma unroll
                for (int j = 0; j < 4; j++)
                    Kp[(size_t)(rowb + j) * 1024 + col] = f2bf(acc[m][n][j] + bv);
            }
        }
    }
}

// ---------------- flash attention: QBLK=128, 8 waves, 3-slot counted ring -------
// (R8 version; partial O now stored as bf16)
__global__ __launch_bounds__(512, 4) void attn_split_kernel(
        const u16* __restrict__ Qp, const u16* __restrict__ Kp,
        const u16* __restrict__ VpT, u16* __restrict__ Opart,
        float* __restrict__ ml) {
    __shared__ u16 lKV[3][2][64 * 64];   // [slot][K=0/V=1] = 49152 B
    const int NT = 16;
    const int tid = threadIdx.x;
    const int lane = tid & 63, wv = tid >> 6;      // wv 0..7
    const int c16 = lane & 15, g = lane >> 4;
    const int bid = blockIdx.x;
    const int qblk = bid >> 7;            // 0..3, high bits
    const int low = bid & 127;
    const int h = low & 15, z = low >> 4;
    const int b = z >> 1, sp = z & 1;
    const int kvbase = sp * 1024;

    const int qrow = b * 512 + qblk * 128 + wv * 16 + c16;
    bf16x8 qf[2];
    qf[0] = *(const bf16x8*)(Qp + (size_t)qrow * 1024 + h * 64 + g * 8);
    qf[1] = *(const bf16x8*)(Qp + (size_t)qrow * 1024 + h * 64 + 32 + g * 8);

    f32x4 acc[4] = {};
    float m_s = -1e30f, l_s = 0.f;       // q = c16, log2 domain

    const int r0 = tid >> 3, c0 = (tid & 7) ^ (r0 & 7);
    const int dstw = wv * 512;           // u16 offset

    auto stageKV = [&](int t) {
        int slot = t % 3;
        int kv0 = kvbase + t * 64;
        u16* dK = &lKV[slot][0][0];
        u16* dV = &lKV[slot][1][0];
        gll16(Kp + (size_t)(b * 2048 + kv0 + r0) * 1024 + h * 64 + c0 * 8, dK + dstw);
        gll16(VpT + (size_t)(h * 64 + r0) * 8192 + b * 2048 + kv0 + c0 * 8, dV + dstw);
    };

    stageKV(0); stageKV(1);
    for (int t = 0; t < NT; ++t) {
        if (t < NT - 2) { WAITV2(); } else { WAITV0(); }
        BAR();
        if (t + 2 < NT) stageKV(t + 2);

        const int slot = t % 3;
        const u16* lK = &lKV[slot][0][0];
        const u16* lV = &lKV[slot][1][0];

        // S^T = K Q^T : s[n][j] = S2[q=c16][key = n*16 + g*4 + j]
        f32x4 s[4];
#pragma unroll
        for (int n = 0; n < 4; n++) {
            s[n] = f32x4{0.f, 0.f, 0.f, 0.f};
            int key = n * 16 + c16;
#pragma unroll
            for (int kk = 0; kk < 2; kk++) {
                bf16x8 kf = *(const bf16x8*)&lK[key * 64 + (((kk * 4 + g) ^ (key & 7))) * 8];
                s[n] = mfma16(kf, qf[kk], s[n]);
            }
        }

        // tree max for q=c16 (+2 shuffles across g groups)
        float mn0 = fmaxf(fmaxf(s[0][0], s[0][1]), fmaxf(s[0][2], s[0][3]));
        float mn1 = fmaxf(fmaxf(s[1][0], s[1][1]), fmaxf(s[1][2], s[1][3]));
        float mn2 = fmaxf(fmaxf(s[2][0], s[2][1]), fmaxf(s[2][2], s[2][3]));
        float mn3 = fmaxf(fmaxf(s[3][0], s[3][1]), fmaxf(s[3][2], s[3][3]));
        float mx = fmaxf(fmaxf(mn0, mn1), fmaxf(mn2, mn3));
        mx = fmaxf(mx, __shfl_xor(mx, 16));
        mx = fmaxf(mx, __shfl_xor(mx, 32));

        // defer-max: rescale only when some row grew by > 8 (log2 domain)
        if (!__all(mx - m_s <= 8.0f)) {
            float mn = fmaxf(m_s, mx);
            float al = exp2f(m_s - mn);
            m_s = mn;
            l_s *= al;
            float alr[4];
#pragma unroll
            for (int j = 0; j < 4; j++) alr[j] = __shfl(al, g * 4 + j);
#pragma unroll
            for (int nd = 0; nd < 4; nd++)
#pragma unroll
                for (int j = 0; j < 4; j++) acc[nd][j] *= alr[j];
        }

        // P = exp2(S2 - m), packed to bf16 pairs in-register
        uint32_t r[4][2];
        float sums[4];
#pragma unroll
        for (int n = 0; n < 4; n++) {
            float p0 = exp2f(s[n][0] - m_s);
            float p1 = exp2f(s[n][1] - m_s);
            float p2 = exp2f(s[n][2] - m_s);
            float p3 = exp2f(s[n][3] - m_s);
            sums[n] = (p0 + p1) + (p2 + p3);
            union { bf16x2 h; uint32_t u; } ca, cb;
            ca.h[0] = (__bf16)p0; ca.h[1] = (__bf16)p1;
            cb.h[0] = (__bf16)p2; cb.h[1] = (__bf16)p3;
            r[n][0] = ca.u; r[n][1] = cb.u;
        }
        float sum = (sums[0] + sums[1]) + (sums[2] + sums[3]);
        sum += __shfl_xor(sum, 16);
        sum += __shfl_xor(sum, 32);
        l_s += sum;

        // O += P @ V : A-fragment fully IN-LANE (VpT columns stored in vslot order)
#pragma unroll
        for (int kk2 = 0; kk2 < 2; kk2++) {
            union { bf16x8 v8; uint32_t u[4]; } pa;
            pa.u[0] = r[kk2 * 2][0];
            pa.u[1] = r[kk2 * 2][1];
            pa.u[2] = r[kk2 * 2 + 1][0];
            pa.u[3] = r[kk2 * 2 + 1][1];
#pragma unroll
            for (int nd = 0; nd < 4; nd++) {
                int d = nd * 16 + c16;
                bf16x8 vf = *(const bf16x8*)&lV[d * 64 + (((kk2 * 4 + g) ^ (d & 7))) * 8];
                acc[nd] = mfma16(pa.v8, vf, acc[nd]);
            }
        }
    }

    // write partials: unnormalized O in bf16 (rows g*4+j) + per-row m,l (g==0)
#pragma unroll
    for (int j = 0; j < 4; j++) {
        int rowq = b * 512 + qblk * 128 + wv * 16 + g * 4 + j;
        size_t idx = (size_t)sp * 32768 + (size_t)rowq * 16 + h;
#pragma unroll
        for (int nd = 0; nd < 4; nd++)
            Opart[idx * 64 + nd * 16 + c16] = f2bf(acc[nd][j]);
    }
    if (g == 0) {
        int rowq = b * 512 + qblk * 128 + wv * 16 + c16;
        size_t idx = (size_t)sp * 32768 + (size_t)rowq * 16 + h;
        ml[idx * 2] = m_s;
        ml[idx * 2 + 1] = l_s;
    }
}

// ---------------- combine the 2 kv-split partials -> X bf16 (log2-domain m) ------
__global__ __launch_bounds__(256) void attn_combine_kernel(
        const u16* __restrict__ Opart, const float* __restrict__ ml,
        u16* __restrict__ X) {
    const int tid = threadIdx.x;
    const int r = blockIdx.x * 4 + (tid >> 6);   // rowhead 0..32767
    const int d = tid & 63;
    float m0 = ml[(size_t)r * 2], l0 = ml[(size_t)r * 2 + 1];
    float m1 = ml[(size_t)(32768 + r) * 2], l1 = ml[(size_t)(32768 + r) * 2 + 1];
    float M = fmaxf(m0, m1);
    float a0 = exp2f(m0 - M), a1 = exp2f(m1 - M);
    float li = 1.f / (l0 * a0 + l1 * a1);
    float o0 = bf2f(Opart[(size_t)r * 64 + d]);
    float o1 = bf2f(Opart[(size_t)(32768 + r) * 64 + d]);
    float o = (o0 * a0 + o1 * a1) * li;
    int qrow = r >> 4, h = r & 15;
    X[(size_t)qrow * 1024 + h * 64 + d] = f2bf(o);
}

// ---------------- launch ----------------
extern "C" void kernel_launch(void* const* d_in, const int* in_sizes, int n_in,
                              void* d_out, int out_size, void* d_ws, size_t ws_size,
                              hipStream_t stream) {
    const float* queries = (const float*)d_in[0];   // [4,512,1024]
    const float* context = (const float*)d_in[1];   // [4,2048,1024]
    const float* Wq      = (const float*)d_in[2];   // [1024,1024]
    const float* bq      = (const float*)d_in[3];   // [1024]
    const float* Wkv     = (const float*)d_in[4];   // [1024,2048]
    const float* bkv     = (const float*)d_in[5];   // [2048]
    const float* Wo      = (const float*)d_in[6];   // [1024,1024]
    const float* bo      = (const float*)d_in[7];   // [1024]

    char* ws = (char*)d_ws;
    u16* qb   = (u16*)(ws);                         // queries bf16   4MB (dead after Q-proj)
    u16* cb   = (u16*)(ws + (4ull  << 20));         // context bf16  16MB (dead after KV GEMM)
    u16* WqT  = (u16*)(ws + (20ull << 20));         // Wq^T bf16      2MB
    u16* WkvT = (u16*)(ws + (22ull << 20));         // Wkv^T bf16     4MB
    u16* WoT  = (u16*)(ws + (26ull << 20));         // Wo^T bf16      2MB
    u16* Qp   = (u16*)(ws + (28ull << 20));         // q proj (x0.125*log2e) 4MB
    u16* Kp   = (u16*)(ws + (32ull << 20));         // k proj        16MB
    u16* VpT  = (u16*)(ws + (48ull << 20));         // v proj ^T (vslot cols) 16MB
    u16* X    = (u16*)(ws + (64ull << 20));         // attn out       4MB
    float* ml    = (float*)qb;                      // 1MB, aliases dead qb
    u16*   Opart = (u16*)cb;                        // 8MB bf16, aliases dead cb

    cast_bf16_kernel<<<dim3(2048), dim3(256), 0, stream>>>(queries, qb, 524288);
    cast_bf16_kernel<<<dim3(8192), dim3(256), 0, stream>>>(context, cb, 2097152);
    trans_cast_kernel<<<dim3(32, 32), dim3(32, 8), 0, stream>>>(Wq, WqT, 1024, 1024);
    trans_cast_kernel<<<dim3(64, 32), dim3(32, 8), 0, stream>>>(Wkv, WkvT, 1024, 2048);
    trans_cast_kernel<<<dim3(32, 32), dim3(32, 8), 0, stream>>>(Wo, WoT, 1024, 1024);

    // scale = 1/8 * log2(e): scores computed directly in exp2 domain
    gemm_bt<0><<<dim3(8, 16), dim3(512), 0, stream>>>(qb, WqT, bq, 2048, 1024, 1024,
                                                      0.18033688f, (void*)Qp);
    gemm_kv_ring<<<dim3(8, 32), dim3(512), 0, stream>>>(cb, WkvT, bkv, Kp, VpT);
    attn_split_kernel<<<dim3(512), dim3(512), 0, stream>>>(Qp, Kp, VpT, Opart, ml);
    attn_combine_kernel<<<dim3(8192), dim3(256), 0, stream>>>(Opart, ml, X);
    gemm_bt<2><<<dim3(8, 16), dim3(512), 0, stream>>>(X, WoT, bo, 2048, 1024, 1024,
                                                      1.0f, d_out);
}

// Round 10
// 125.932 us; speedup vs baseline: 1.4215x; 1.0446x over previous
//
#include <hip/hip_runtime.h>
#include <hip/hip_bf16.h>
#include <stdint.h>

typedef unsigned short u16;
typedef __attribute__((ext_vector_type(8))) __bf16 bf16x8;
typedef __attribute__((ext_vector_type(2))) __bf16 bf16x2;
typedef __attribute__((ext_vector_type(4))) float f32x4;
typedef __attribute__((ext_vector_type(4))) u16 u16x4;
typedef __attribute__((ext_vector_type(4))) float f32x4v;

typedef __attribute__((address_space(1))) void gvoid_t;
typedef __attribute__((address_space(3))) void lvoid_t;

#define BAR()    asm volatile("s_barrier" ::: "memory")
#define WAITV0() asm volatile("s_waitcnt vmcnt(0)" ::: "memory")
#define WAITV2() asm volatile("s_waitcnt vmcnt(2)" ::: "memory")
#define WAITV4() asm volatile("s_waitcnt vmcnt(4)" ::: "memory")
#define WAITV8() asm volatile("s_waitcnt vmcnt(8)" ::: "memory")

__device__ inline u16 f2bf(float f) {
    uint32_t u = __float_as_uint(f);
    u += 0x7fff + ((u >> 16) & 1);   // RNE
    return (u16)(u >> 16);
}

__device__ inline float bf2f(u16 v) {
    return __uint_as_float(((uint32_t)v) << 16);
}

__device__ inline void gll16(const void* g, void* l) {
    __builtin_amdgcn_global_load_lds((gvoid_t*)g, (lvoid_t*)l, 16, 0, 0);
}

__device__ inline f32x4 mfma16(bf16x8 a, bf16x8 b, f32x4 c) {
    return __builtin_amdgcn_mfma_f32_16x16x32_bf16(a, b, c, 0, 0, 0);
}

// V slot permutation: context row r (mod 64) -> storage slot, so that the PV
// A-fragment is IN-LANE after swapped QK^T (keys n*16+g*4+j live in lane g).
__device__ inline int vslot(int r) {
    int n = r >> 4;
    return ((n >> 1) << 5) + (((r >> 2) & 3) << 3) + ((n & 1) << 2) + (r & 3);
}

// ---------------- fused cast fp32 -> bf16 (queries + context) ----------------
__global__ __launch_bounds__(256) void prep_cast_kernel(
        const float* __restrict__ q, const float* __restrict__ c,
        u16* __restrict__ qb, u16* __restrict__ cb) {
    int i = blockIdx.x * 256 + threadIdx.x;
    const float* src; u16* dst; int j;
    if (i < 524288) { src = q; dst = qb; j = i; }
    else            { src = c; dst = cb; j = i - 524288; }
    f32x4v f = ((const f32x4v*)src)[j];
    u16x4 o;
    o[0] = f2bf(f[0]); o[1] = f2bf(f[1]); o[2] = f2bf(f[2]); o[3] = f2bf(f[3]);
    ((u16x4*)dst)[j] = o;
}

// ---------------- fused transpose+cast for Wq/Wkv/Wo (z selects) ----------------
__global__ __launch_bounds__(256) void prep_trans_kernel(
        const float* __restrict__ Wq, const float* __restrict__ Wkv,
        const float* __restrict__ Wo, u16* __restrict__ WqT,
        u16* __restrict__ WkvT, u16* __restrict__ WoT) {
    const int zz = blockIdx.z;
    const float* W = (zz == 0) ? Wq : (zz == 1) ? Wkv : Wo;
    u16* WT = (zz == 0) ? WqT : (zz == 1) ? WkvT : WoT;
    const int N = (zz == 1) ? 2048 : 1024;
    const int K = 1024;
    if (blockIdx.x * 32 >= N) return;
    __shared__ float t[32][33];
    int x = threadIdx.x & 31;
    int y = threadIdx.x >> 5;            // 0..7
    int n0 = blockIdx.x * 32;
    int k0 = blockIdx.y * 32;
    for (int yy = y; yy < 32; yy += 8)
        t[yy][x] = W[(size_t)(k0 + yy) * N + n0 + x];
    __syncthreads();
    for (int yy = y; yy < 32; yy += 8)
        WT[(size_t)(n0 + yy) * K + k0 + x] = f2bf(t[x][yy]);
}

// ---------------- small GEMM: 128x128 tile, 8 waves, 4-slot counted ring --------
// MODE 0: out0 = bf16[M][N], value=(acc+bias)*scale     (Q proj)
// MODE 2: out0 = fp32 [M][N]                            (O proj -> d_out)
template <int MODE>
__global__ __launch_bounds__(512, 2) void gemm_bt(
        const u16* __restrict__ A, const u16* __restrict__ Bt,
        const float* __restrict__ bias, int M, int N, int K,
        float scale, void* __restrict__ out0) {
    __shared__ u16 lds[4][2][128 * 32];   // 4 slots x (A,B) x 8KB = 64KB
    const int NT = K >> 5;                // K/32
    const int tid = threadIdx.x;          // 0..511
    const int lane = tid & 63, wv = tid >> 6;   // wv 0..7
    const int c16 = lane & 15, g = lane >> 4;
    const int m0 = blockIdx.y * 128, n0 = blockIdx.x * 128;

    const int r0 = tid >> 2, cc0 = (tid & 3) ^ ((r0 >> 1) & 3);
    const size_t offA = (size_t)(m0 + r0) * K + cc0 * 8;
    const size_t offB = (size_t)(n0 + r0) * K + cc0 * 8;
    const int dstw = wv * 512;            // wave-uniform u16 base (lane*16B by HW)

    auto stage = [&](int t) {
        gll16(A + offA + t * 32, &lds[t & 3][0][0] + dstw);
        gll16(Bt + offB + t * 32, &lds[t & 3][1][0] + dstw);
    };

    const int wm = (wv >> 1) * 32, wn = (wv & 1) * 64;
    f32x4 acc[2][4] = {};

    auto compute = [&](int slot) {
        const u16* la = &lds[slot][0][0];
        const u16* lb = &lds[slot][1][0];
        bf16x8 af[2], bfr[4];
#pragma unroll
        for (int m = 0; m < 2; m++) {
            int row = wm + m * 16 + c16;
            af[m] = *(const bf16x8*)&la[row * 32 + (g ^ ((row >> 1) & 3)) * 8];
        }
#pragma unroll
        for (int n = 0; n < 4; n++) {
            int row = wn + n * 16 + c16;
            bfr[n] = *(const bf16x8*)&lb[row * 32 + (g ^ ((row >> 1) & 3)) * 8];
        }
#pragma unroll
        for (int m = 0; m < 2; m++)
#pragma unroll
            for (int n = 0; n < 4; n++)
                acc[m][n] = mfma16(af[m], bfr[n], acc[m][n]);
    };

    stage(0); stage(1); stage(2);        // 6 loads/wave in flight

    for (int t = 0; t < NT - 2; ++t) {
        WAITV4();
        BAR();
        if (t + 3 < NT) stage(t + 3);
        compute(t & 3);
    }
    WAITV2(); BAR(); compute((NT - 2) & 3);
    WAITV0(); BAR(); compute((NT - 1) & 3);

#pragma unroll
    for (int n = 0; n < 4; n++) {
        int col = n0 + wn + n * 16 + c16;
        float bv = bias[col];
#pragma unroll
        for (int m = 0; m < 2; m++) {
            int rowb = m0 + wm + m * 16 + g * 4;
#pragma unroll
            for (int j = 0; j < 4; j++) {
                float v = (acc[m][n][j] + bv) * scale;
                int row = rowb + j;
                if (MODE == 0) {
                    ((u16*)out0)[(size_t)row * N + col] = f2bf(v);
                } else {
                    ((float*)out0)[(size_t)row * N + col] = v;
                }
            }
        }
    }
}

// ---------------- big GEMM: 256x256 tile, 8 waves, 4-deep ring, counted vmcnt ----
// (R6-proven version; 44 us, 0 conflicts)
__global__ __launch_bounds__(512, 2) void gemm_kv_ring(
        const u16* __restrict__ A, const u16* __restrict__ Bt,
        const float* __restrict__ bias, u16* __restrict__ Kp,
        u16* __restrict__ VpT) {
    __shared__ u16 lds[4][2][256 * 32];   // [slot][A=0/B=1][row*32 + swz-chunk*8]
    const int K = 1024, NT = 32;          // K / 32
    const int tid = threadIdx.x;
    const int lane = tid & 63, wv = tid >> 6;
    const int c16 = lane & 15, g = lane >> 4;

    const int nwg = gridDim.x * gridDim.y;
    const int bid = blockIdx.y * gridDim.x + blockIdx.x;
    const int cpx = nwg >> 3;
    const int sw = (bid & 7) * cpx + (bid >> 3);
    const int bx = sw % gridDim.x, by = sw / gridDim.x;
    const int m0 = by * 256, n0 = bx * 256;

    const int isB = wv >> 2;
    const int rbase = (wv & 3) * 64;
    const u16* src = isB ? Bt : A;
    const int base0 = isB ? n0 : m0;
    size_t off[4];
    const u16* ldst[4];
#pragma unroll
    for (int i = 0; i < 4; i++) {
        int rl = rbase + i * 16 + (lane >> 2);
        int ch = (lane & 3) ^ ((rl >> 1) & 3);
        off[i] = (size_t)(base0 + rl) * K + ch * 8;
        ldst[i] = &lds[0][0][0] + ((size_t)isB * 256 * 32) + (size_t)(rbase + i * 16) * 32;
    }
    const size_t slotStride = 2 * 256 * 32;

    auto stage = [&](int t) {
        const u16* s0 = src + (size_t)t * 32;
        u16* d = (u16*)ldst[0] + (size_t)(t & 3) * slotStride;
        gll16(s0 + off[0], d);
        gll16(s0 + off[1], d + 16 * 32);
        gll16(s0 + off[2], d + 32 * 32);
        gll16(s0 + off[3], d + 48 * 32);
    };

    const int wm = wv >> 2;
    const int wn = wv & 3;
    f32x4 acc[8][4] = {};

    auto compute = [&](int slot) {
        const u16* la = &lds[slot][0][0];
        const u16* lb = &lds[slot][1][0];
        bf16x8 af[8], bfr[4];
#pragma unroll
        for (int m = 0; m < 8; m++) {
            int row = wm * 128 + m * 16 + c16;
            af[m] = *(const bf16x8*)&la[row * 32 + (g ^ ((row >> 1) & 3)) * 8];
        }
#pragma unroll
        for (int n = 0; n < 4; n++) {
            int row = wn * 64 + n * 16 + c16;
            bfr[n] = *(const bf16x8*)&lb[row * 32 + (g ^ ((row >> 1) & 3)) * 8];
        }
#pragma unroll
        for (int m = 0; m < 8; m++)
#pragma unroll
            for (int n = 0; n < 4; n++)
                acc[m][n] = mfma16(af[m], bfr[n], acc[m][n]);
    };

    stage(0); stage(1); stage(2);

    for (int t = 0; t < NT - 2; ++t) {
        WAITV8();
        BAR();
        if (t + 3 < NT) stage(t + 3);
        compute(t & 3);
    }
    WAITV4(); BAR(); compute((NT - 2) & 3);
    WAITV0(); BAR(); compute((NT - 1) & 3);

    const bool isV = (n0 >= 1024);
#pragma unroll
    for (int n = 0; n < 4; n++) {
        int col = n0 + wn * 64 + n * 16 + c16;
        float bv = bias[col];
#pragma unroll
        for (int m = 0; m < 8; m++) {
            int rowb = m0 + wm * 128 + m * 16 + g * 4;
            if (isV) {
                u16x4 pk;
#pragma unroll
                for (int j = 0; j < 4; j++) pk[j] = f2bf(acc[m][n][j] + bv);
                int vcol = (rowb & ~63) + vslot(rowb & 63);
                *(u16x4*)&VpT[(size_t)(col - 1024) * 8192 + vcol] = pk;
            } else {
#pragma unroll
                for (int j = 0; j < 4; j++)
                    Kp[(size_t)(rowb + j) * 1024 + col] = f2bf(acc[m][n][j] + bv);
            }
        }
    }
}

// ---------------- flash attention: QBLK=128, 4 waves x 2 q-sets, 3-slot ring ----
// Each wave owns 32 q-rows (2 q-sets of 16). K/V LDS fragments are read ONCE per
// tile and feed both q-sets' MFMAs -> LDS-read bytes per unit work HALVED (the
// measured bottleneck). grid 512, LDS 48KB -> 2 blocks/CU; launch_bounds(256,3)
// caps VGPR at ~168. Counted vmcnt(4) ring (4 gll16/thread/tile, depth 2).
__global__ __launch_bounds__(256, 3) void attn_split_kernel(
        const u16* __restrict__ Qp, const u16* __restrict__ Kp,
        const u16* __restrict__ VpT, u16* __restrict__ Opart,
        float* __restrict__ ml) {
    __shared__ u16 lKV[3][2][64 * 64];   // [slot][K=0/V=1] = 49152 B
    const int NT = 16;
    const int tid = threadIdx.x;
    const int lane = tid & 63, wv = tid >> 6;      // wv 0..3
    const int c16 = lane & 15, g = lane >> 4;
    const int bid = blockIdx.x;
    const int qblk = bid >> 7;            // 0..3, high bits (XCD slab grouping)
    const int low = bid & 127;
    const int h = low & 15, z = low >> 4;
    const int b = z >> 1, sp = z & 1;
    const int kvbase = sp * 1024;

    bf16x8 qf[2][2];
#pragma unroll
    for (int qs = 0; qs < 2; qs++) {
        int qrow = b * 512 + qblk * 128 + qs * 64 + wv * 16 + c16;
        qf[qs][0] = *(const bf16x8*)(Qp + (size_t)qrow * 1024 + h * 64 + g * 8);
        qf[qs][1] = *(const bf16x8*)(Qp + (size_t)qrow * 1024 + h * 64 + 32 + g * 8);
    }

    f32x4 acc[2][4] = {};
    float m_s[2] = {-1e30f, -1e30f}, l_s[2] = {0.f, 0.f};   // log2 domain

    // staging: 256 threads, 2 entries each per matrix (R6-proven pattern)
    const int r0 = tid >> 3, c0 = (tid & 7) ^ (r0 & 7);
    const int r1 = 32 + r0,  c1 = (tid & 7) ^ (r1 & 7);
    const int dst0 = wv * 512, dst1 = 2048 + wv * 512;   // u16 offsets

    auto stageKV = [&](int t) {
        int slot = t % 3;
        int kv0 = kvbase + t * 64;
        u16* dK = &lKV[slot][0][0];
        u16* dV = &lKV[slot][1][0];
        gll16(Kp + (size_t)(b * 2048 + kv0 + r0) * 1024 + h * 64 + c0 * 8, dK + dst0);
        gll16(Kp + (size_t)(b * 2048 + kv0 + r1) * 1024 + h * 64 + c1 * 8, dK + dst1);
        gll16(VpT + (size_t)(h * 64 + r0) * 8192 + b * 2048 + kv0 + c0 * 8, dV + dst0);
        gll16(VpT + (size_t)(h * 64 + r1) * 8192 + b * 2048 + kv0 + c1 * 8, dV + dst1);
    };

    stageKV(0); stageKV(1);
    for (int t = 0; t < NT; ++t) {
        if (t < NT - 1) { WAITV4(); } else { WAITV0(); }
        BAR();
        if (t + 2 < NT) stageKV(t + 2);

        const int slot = t % 3;
        const u16* lK = &lKV[slot][0][0];
        const u16* lV = &lKV[slot][1][0];

        // S^T = K Q^T for both q-sets; K fragments read once
        f32x4 s[2][4];
#pragma unroll
        for (int n = 0; n < 4; n++) {
            s[0][n] = f32x4{0.f, 0.f, 0.f, 0.f};
            s[1][n] = f32x4{0.f, 0.f, 0.f, 0.f};
        }
#pragma unroll
        for (int n = 0; n < 4; n++) {
            int key = n * 16 + c16;
#pragma unroll
            for (int kk = 0; kk < 2; kk++) {
                bf16x8 kf = *(const bf16x8*)&lK[key * 64 + (((kk * 4 + g) ^ (key & 7))) * 8];
                s[0][n] = mfma16(kf, qf[0][kk], s[0][n]);
                s[1][n] = mfma16(kf, qf[1][kk], s[1][n]);
            }
        }

        // per-q-set online softmax (q = c16), in-register + 2 shuffles each
        uint32_t r[2][4][2];
#pragma unroll
        for (int qs = 0; qs < 2; qs++) {
            float mn0 = fmaxf(fmaxf(s[qs][0][0], s[qs][0][1]), fmaxf(s[qs][0][2], s[qs][0][3]));
            float mn1 = fmaxf(fmaxf(s[qs][1][0], s[qs][1][1]), fmaxf(s[qs][1][2], s[qs][1][3]));
            float mn2 = fmaxf(fmaxf(s[qs][2][0], s[qs][2][1]), fmaxf(s[qs][2][2], s[qs][2][3]));
            float mn3 = fmaxf(fmaxf(s[qs][3][0], s[qs][3][1]), fmaxf(s[qs][3][2], s[qs][3][3]));
            float mx = fmaxf(fmaxf(mn0, mn1), fmaxf(mn2, mn3));
            mx = fmaxf(mx, __shfl_xor(mx, 16));
            mx = fmaxf(mx, __shfl_xor(mx, 32));

            if (!__all(mx - m_s[qs] <= 8.0f)) {
                float mn = fmaxf(m_s[qs], mx);
                float al = exp2f(m_s[qs] - mn);
                m_s[qs] = mn;
                l_s[qs] *= al;
                float alr[4];
#pragma unroll
                for (int j = 0; j < 4; j++) alr[j] = __shfl(al, g * 4 + j);
#pragma unroll
                for (int nd = 0; nd < 4; nd++)
#pragma unroll
                    for (int j = 0; j < 4; j++) acc[qs][nd][j] *= alr[j];
            }

            float sums[4];
#pragma unroll
            for (int n = 0; n < 4; n++) {
                float p0 = exp2f(s[qs][n][0] - m_s[qs]);
                float p1 = exp2f(s[qs][n][1] - m_s[qs]);
                float p2 = exp2f(s[qs][n][2] - m_s[qs]);
                float p3 = exp2f(s[qs][n][3] - m_s[qs]);
                sums[n] = (p0 + p1) + (p2 + p3);
                union { bf16x2 h; uint32_t u; } ca, cb;
                ca.h[0] = (__bf16)p0; ca.h[1] = (__bf16)p1;
                cb.h[0] = (__bf16)p2; cb.h[1] = (__bf16)p3;
                r[qs][n][0] = ca.u; r[qs][n][1] = cb.u;
            }
            float sum = (sums[0] + sums[1]) + (sums[2] + sums[3]);
            sum += __shfl_xor(sum, 16);
            sum += __shfl_xor(sum, 32);
            l_s[qs] += sum;
        }

        // O += P @ V for both q-sets; V fragments read once
#pragma unroll
        for (int kk2 = 0; kk2 < 2; kk2++) {
            union { bf16x8 v8; uint32_t u[4]; } pa0, pa1;
            pa0.u[0] = r[0][kk2 * 2][0];     pa0.u[1] = r[0][kk2 * 2][1];
            pa0.u[2] = r[0][kk2 * 2 + 1][0]; pa0.u[3] = r[0][kk2 * 2 + 1][1];
            pa1.u[0] = r[1][kk2 * 2][0];     pa1.u[1] = r[1][kk2 * 2][1];
            pa1.u[2] = r[1][kk2 * 2 + 1][0]; pa1.u[3] = r[1][kk2 * 2 + 1][1];
#pragma unroll
            for (int nd = 0; nd < 4; nd++) {
                int d = nd * 16 + c16;
                bf16x8 vf = *(const bf16x8*)&lV[d * 64 + (((kk2 * 4 + g) ^ (d & 7))) * 8];
                acc[0][nd] = mfma16(pa0.v8, vf, acc[0][nd]);
                acc[1][nd] = mfma16(pa1.v8, vf, acc[1][nd]);
            }
        }
    }

    // write partials: unnormalized O in bf16 + per-row m,l (g==0 lanes)
#pragma unroll
    for (int qs = 0; qs < 2; qs++) {
#pragma unroll
        for (int j = 0; j < 4; j++) {
            int rowq = b * 512 + qblk * 128 + qs * 64 + wv * 16 + g * 4 + j;
            size_t idx = (size_t)sp * 32768 + (size_t)rowq * 16 + h;
#pragma unroll
            for (int nd = 0; nd < 4; nd++)
                Opart[idx * 64 + nd * 16 + c16] = f2bf(acc[qs][nd][j]);
        }
        if (g == 0) {
            int rowq = b * 512 + qblk * 128 + qs * 64 + wv * 16 + c16;
            size_t idx = (size_t)sp * 32768 + (size_t)rowq * 16 + h;
            ml[idx * 2] = m_s[qs];
            ml[idx * 2 + 1] = l_s[qs];
        }
    }
}

// ---------------- combine the 2 kv-split partials -> X bf16 (log2-domain m) ------
__global__ __launch_bounds__(256) void attn_combine_kernel(
        const u16* __restrict__ Opart, const float* __restrict__ ml,
        u16* __restrict__ X) {
    const int tid = threadIdx.x;
    const int r = blockIdx.x * 4 + (tid >> 6);   // rowhead 0..32767
    const int d = tid & 63;
    float m0 = ml[(size_t)r * 2], l0 = ml[(size_t)r * 2 + 1];
    float m1 = ml[(size_t)(32768 + r) * 2], l1 = ml[(size_t)(32768 + r) * 2 + 1];
    float M = fmaxf(m0, m1);
    float a0 = exp2f(m0 - M), a1 = exp2f(m1 - M);
    float li = 1.f / (l0 * a0 + l1 * a1);
    float o0 = bf2f(Opart[(size_t)r * 64 + d]);
    float o1 = bf2f(Opart[(size_t)(32768 + r) * 64 + d]);
    float o = (o0 * a0 + o1 * a1) * li;
    int qrow = r >> 4, h = r & 15;
    X[(size_t)qrow * 1024 + h * 64 + d] = f2bf(o);
}

// ---------------- launch ----------------
extern "C" void kernel_launch(void* const* d_in, const int* in_sizes, int n_in,
                              void* d_out, int out_size, void* d_ws, size_t ws_size,
                              hipStream_t stream) {
    const float* queries = (const float*)d_in[0];   // [4,512,1024]
    const float* context = (const float*)d_in[1];   // [4,2048,1024]
    const float* Wq      = (const float*)d_in[2];   // [1024,1024]
    const float* bq      = (const float*)d_in[3];   // [1024]
    const float* Wkv     = (const float*)d_in[4];   // [1024,2048]
    const float* bkv     = (const float*)d_in[5];   // [2048]
    const float* Wo      = (const float*)d_in[6];   // [1024,1024]
    const float* bo      = (const float*)d_in[7];   // [1024]

    char* ws = (char*)d_ws;
    u16* qb   = (u16*)(ws);                         // queries bf16   4MB (dead after Q-proj)
    u16* cb   = (u16*)(ws + (4ull  << 20));         // context bf16  16MB (dead after KV GEMM)
    u16* WqT  = (u16*)(ws + (20ull << 20));         // Wq^T bf16      2MB
    u16* WkvT = (u16*)(ws + (22ull << 20));         // Wkv^T bf16     4MB
    u16* WoT  = (u16*)(ws + (26ull << 20));         // Wo^T bf16      2MB
    u16* Qp   = (u16*)(ws + (28ull << 20));         // q proj (x0.125*log2e) 4MB
    u16* Kp   = (u16*)(ws + (32ull << 20));         // k proj        16MB
    u16* VpT  = (u16*)(ws + (48ull << 20));         // v proj ^T (vslot cols) 16MB
    u16* X    = (u16*)(ws + (64ull << 20));         // attn out       4MB
    float* ml    = (float*)qb;                      // 1MB, aliases dead qb
    u16*   Opart = (u16*)cb;                        // 8MB bf16, aliases dead cb

    prep_cast_kernel<<<dim3(10240), dim3(256), 0, stream>>>(queries, context, qb, cb);
    prep_trans_kernel<<<dim3(64, 32, 3), dim3(256), 0, stream>>>(Wq, Wkv, Wo,
                                                                 WqT, WkvT, WoT);

    // scale = 1/8 * log2(e): scores computed directly in exp2 domain
    gemm_bt<0><<<dim3(8, 16), dim3(512), 0, stream>>>(qb, WqT, bq, 2048, 1024, 1024,
                                                      0.18033688f, (void*)Qp);
    gemm_kv_ring<<<dim3(8, 32), dim3(512), 0, stream>>>(cb, WkvT, bkv, Kp, VpT);
    attn_split_kernel<<<dim3(512), dim3(256), 0, stream>>>(Qp, Kp, VpT, Opart, ml);
    attn_combine_kernel<<<dim3(8192), dim3(256), 0, stream>>>(Opart, ml, X);
    gemm_bt<2><<<dim3(8, 16), dim3(512), 0, stream>>>(X, WoT, bo, 2048, 1024, 1024,
                                                      1.0f, d_out);
}

// Round 11
// 124.132 us; speedup vs baseline: 1.4421x; 1.0145x over previous
//
#include <hip/hip_runtime.h>
#include <hip/hip_bf16.h>
#include <stdint.h>

typedef unsigned short u16;
typedef __attribute__((ext_vector_type(8))) __bf16 bf16x8;
typedef __attribute__((ext_vector_type(2))) __bf16 bf16x2;
typedef __attribute__((ext_vector_type(4))) float f32x4;
typedef __attribute__((ext_vector_type(4))) u16 u16x4;
typedef __attribute__((ext_vector_type(4))) float f32x4v;

typedef __attribute__((address_space(1))) void gvoid_t;
typedef __attribute__((address_space(3))) void lvoid_t;

#define BAR()    asm volatile("s_barrier" ::: "memory")
#define WAITV0() asm volatile("s_waitcnt vmcnt(0)" ::: "memory")
#define WAITV2() asm volatile("s_waitcnt vmcnt(2)" ::: "memory")
#define WAITV4() asm volatile("s_waitcnt vmcnt(4)" ::: "memory")
#define WAITV8() asm volatile("s_waitcnt vmcnt(8)" ::: "memory")

__device__ inline u16 f2bf(float f) {
    uint32_t u = __float_as_uint(f);
    u += 0x7fff + ((u >> 16) & 1);   // RNE
    return (u16)(u >> 16);
}

__device__ inline float bf2f(u16 v) {
    return __uint_as_float(((uint32_t)v) << 16);
}

__device__ inline void gll16(const void* g, void* l) {
    __builtin_amdgcn_global_load_lds((gvoid_t*)g, (lvoid_t*)l, 16, 0, 0);
}

__device__ inline f32x4 mfma16(bf16x8 a, bf16x8 b, f32x4 c) {
    return __builtin_amdgcn_mfma_f32_16x16x32_bf16(a, b, c, 0, 0, 0);
}

// V slot permutation: context row r (mod 64) -> storage slot, so that the PV
// A-fragment is IN-LANE after swapped QK^T (keys n*16+g*4+j live in lane g).
__device__ inline int vslot(int r) {
    int n = r >> 4;
    return ((n >> 1) << 5) + (((r >> 2) & 3) << 3) + ((n & 1) << 2) + (r & 3);
}

// ---------------- fused prep: casts (blocks 0..10239) + transposes (10240..14335)
__global__ __launch_bounds__(256) void prep_kernel(
        const float* __restrict__ q, const float* __restrict__ c,
        const float* __restrict__ Wq, const float* __restrict__ Wkv,
        const float* __restrict__ Wo, u16* __restrict__ qb,
        u16* __restrict__ cb, u16* __restrict__ WqT,
        u16* __restrict__ WkvT, u16* __restrict__ WoT) {
    const int bid = blockIdx.x;
    const int tid = threadIdx.x;
    if (bid < 10240) {
        // vectorized fp32 -> bf16 cast of queries (first 524288 x4) + context
        int i = bid * 256 + tid;
        const float* src; u16* dst; int j;
        if (i < 524288) { src = q; dst = qb; j = i; }
        else            { src = c; dst = cb; j = i - 524288; }
        f32x4v f = ((const f32x4v*)src)[j];
        u16x4 o;
        o[0] = f2bf(f[0]); o[1] = f2bf(f[1]); o[2] = f2bf(f[2]); o[3] = f2bf(f[3]);
        ((u16x4*)dst)[j] = o;
        return;
    }
    // transpose+cast W[K=1024][N] -> WT[N][1024]
    int b2 = bid - 10240;
    const float* W; u16* WT; int N, n0, k0;
    if (b2 < 1024)      { W = Wq;  WT = WqT;  N = 1024; n0 = (b2 & 31) * 32; k0 = (b2 >> 5) * 32; }
    else if (b2 < 3072) { int b3 = b2 - 1024; W = Wkv; WT = WkvT; N = 2048; n0 = (b3 & 63) * 32; k0 = (b3 >> 6) * 32; }
    else                { int b3 = b2 - 3072; W = Wo;  WT = WoT;  N = 1024; n0 = (b3 & 31) * 32; k0 = (b3 >> 5) * 32; }
    __shared__ float t[32][33];
    int x = tid & 31, y = tid >> 5;
    for (int yy = y; yy < 32; yy += 8)
        t[yy][x] = W[(size_t)(k0 + yy) * N + n0 + x];
    __syncthreads();
    for (int yy = y; yy < 32; yy += 8)
        WT[(size_t)(n0 + yy) * 1024 + k0 + x] = f2bf(t[x][yy]);
}

// ---------------- small GEMM: 128x128 tile, 8 waves, 4-slot counted ring --------
// MODE 0: out0 = bf16[M][N], value=(acc+bias)*scale     (Q proj)
// MODE 2: out0 = fp32 [M][N]                            (O proj -> d_out)
template <int MODE>
__global__ __launch_bounds__(512, 2) void gemm_bt(
        const u16* __restrict__ A, const u16* __restrict__ Bt,
        const float* __restrict__ bias, int M, int N, int K,
        float scale, void* __restrict__ out0) {
    __shared__ u16 lds[4][2][128 * 32];   // 4 slots x (A,B) x 8KB = 64KB
    const int NT = K >> 5;                // K/32
    const int tid = threadIdx.x;          // 0..511
    const int lane = tid & 63, wv = tid >> 6;   // wv 0..7
    const int c16 = lane & 15, g = lane >> 4;
    const int m0 = blockIdx.y * 128, n0 = blockIdx.x * 128;

    const int r0 = tid >> 2, cc0 = (tid & 3) ^ ((r0 >> 1) & 3);
    const size_t offA = (size_t)(m0 + r0) * K + cc0 * 8;
    const size_t offB = (size_t)(n0 + r0) * K + cc0 * 8;
    const int dstw = wv * 512;            // wave-uniform u16 base (lane*16B by HW)

    auto stage = [&](int t) {
        gll16(A + offA + t * 32, &lds[t & 3][0][0] + dstw);
        gll16(Bt + offB + t * 32, &lds[t & 3][1][0] + dstw);
    };

    const int wm = (wv >> 1) * 32, wn = (wv & 1) * 64;
    f32x4 acc[2][4] = {};

    auto compute = [&](int slot) {
        const u16* la = &lds[slot][0][0];
        const u16* lb = &lds[slot][1][0];
        bf16x8 af[2], bfr[4];
#pragma unroll
        for (int m = 0; m < 2; m++) {
            int row = wm + m * 16 + c16;
            af[m] = *(const bf16x8*)&la[row * 32 + (g ^ ((row >> 1) & 3)) * 8];
        }
#pragma unroll
        for (int n = 0; n < 4; n++) {
            int row = wn + n * 16 + c16;
            bfr[n] = *(const bf16x8*)&lb[row * 32 + (g ^ ((row >> 1) & 3)) * 8];
        }
#pragma unroll
        for (int m = 0; m < 2; m++)
#pragma unroll
            for (int n = 0; n < 4; n++)
                acc[m][n] = mfma16(af[m], bfr[n], acc[m][n]);
    };

    stage(0); stage(1); stage(2);        // 6 loads/wave in flight

    for (int t = 0; t < NT - 2; ++t) {
        WAITV4();
        BAR();
        if (t + 3 < NT) stage(t + 3);
        compute(t & 3);
    }
    WAITV2(); BAR(); compute((NT - 2) & 3);
    WAITV0(); BAR(); compute((NT - 1) & 3);

#pragma unroll
    for (int n = 0; n < 4; n++) {
        int col = n0 + wn + n * 16 + c16;
        float bv = bias[col];
#pragma unroll
        for (int m = 0; m < 2; m++) {
            int rowb = m0 + wm + m * 16 + g * 4;
#pragma unroll
            for (int j = 0; j < 4; j++) {
                float v = (acc[m][n][j] + bv) * scale;
                int row = rowb + j;
                if (MODE == 0) {
                    ((u16*)out0)[(size_t)row * N + col] = f2bf(v);
                } else {
                    ((float*)out0)[(size_t)row * N + col] = v;
                }
            }
        }
    }
}

// ---------------- big GEMM: 256x256 tile, 8 waves, 4-deep ring, counted vmcnt ----
// (R6-proven version; 44 us, 0 conflicts)
__global__ __launch_bounds__(512, 2) void gemm_kv_ring(
        const u16* __restrict__ A, const u16* __restrict__ Bt,
        const float* __restrict__ bias, u16* __restrict__ Kp,
        u16* __restrict__ VpT) {
    __shared__ u16 lds[4][2][256 * 32];   // [slot][A=0/B=1][row*32 + swz-chunk*8]
    const int K = 1024, NT = 32;          // K / 32
    const int tid = threadIdx.x;
    const int lane = tid & 63, wv = tid >> 6;
    const int c16 = lane & 15, g = lane >> 4;

    const int nwg = gridDim.x * gridDim.y;
    const int bid = blockIdx.y * gridDim.x + blockIdx.x;
    const int cpx = nwg >> 3;
    const int sw = (bid & 7) * cpx + (bid >> 3);
    const int bx = sw % gridDim.x, by = sw / gridDim.x;
    const int m0 = by * 256, n0 = bx * 256;

    const int isB = wv >> 2;
    const int rbase = (wv & 3) * 64;
    const u16* src = isB ? Bt : A;
    const int base0 = isB ? n0 : m0;
    size_t off[4];
    const u16* ldst[4];
#pragma unroll
    for (int i = 0; i < 4; i++) {
        int rl = rbase + i * 16 + (lane >> 2);
        int ch = (lane & 3) ^ ((rl >> 1) & 3);
        off[i] = (size_t)(base0 + rl) * K + ch * 8;
        ldst[i] = &lds[0][0][0] + ((size_t)isB * 256 * 32) + (size_t)(rbase + i * 16) * 32;
    }
    const size_t slotStride = 2 * 256 * 32;

    auto stage = [&](int t) {
        const u16* s0 = src + (size_t)t * 32;
        u16* d = (u16*)ldst[0] + (size_t)(t & 3) * slotStride;
        gll16(s0 + off[0], d);
        gll16(s0 + off[1], d + 16 * 32);
        gll16(s0 + off[2], d + 32 * 32);
        gll16(s0 + off[3], d + 48 * 32);
    };

    const int wm = wv >> 2;
    const int wn = wv & 3;
    f32x4 acc[8][4] = {};

    auto compute = [&](int slot) {
        const u16* la = &lds[slot][0][0];
        const u16* lb = &lds[slot][1][0];
        bf16x8 af[8], bfr[4];
#pragma unroll
        for (int m = 0; m < 8; m++) {
            int row = wm * 128 + m * 16 + c16;
            af[m] = *(const bf16x8*)&la[row * 32 + (g ^ ((row >> 1) & 3)) * 8];
        }
#pragma unroll
        for (int n = 0; n < 4; n++) {
            int row = wn * 64 + n * 16 + c16;
            bfr[n] = *(const bf16x8*)&lb[row * 32 + (g ^ ((row >> 1) & 3)) * 8];
        }
#pragma unroll
        for (int m = 0; m < 8; m++)
#pragma unroll
            for (int n = 0; n < 4; n++)
                acc[m][n] = mfma16(af[m], bfr[n], acc[m][n]);
    };

    stage(0); stage(1); stage(2);

    for (int t = 0; t < NT - 2; ++t) {
        WAITV8();
        BAR();
        if (t + 3 < NT) stage(t + 3);
        compute(t & 3);
    }
    WAITV4(); BAR(); compute((NT - 2) & 3);
    WAITV0(); BAR(); compute((NT - 1) & 3);

    const bool isV = (n0 >= 1024);
#pragma unroll
    for (int n = 0; n < 4; n++) {
        int col = n0 + wn * 64 + n * 16 + c16;
        float bv = bias[col];
#pragma unroll
        for (int m = 0; m < 8; m++) {
            int rowb = m0 + wm * 128 + m * 16 + g * 4;
            if (isV) {
                u16x4 pk;
#pragma unroll
                for (int j = 0; j < 4; j++) pk[j] = f2bf(acc[m][n][j] + bv);
                int vcol = (rowb & ~63) + vslot(rowb & 63);
                *(u16x4*)&VpT[(size_t)(col - 1024) * 8192 + vcol] = pk;
            } else {
#pragma unroll
                for (int j = 0; j < 4; j++)
                    Kp[(size_t)(rowb + j) * 1024 + col] = f2bf(acc[m][n][j] + bv);
            }
        }
    }
}

// ---------------- flash attention: QBLK=128, 4 waves x 2 q-sets, kv-split x4 ----
// grid 1024 (1-D): qblk(2b) in HIGH bits (bid>>8) -> KV-sharing blocks land on one
// XCD. 3 blocks/CU now reachable (grid 4/CU, LDS caps at 3) -> 12 waves/CU TLP.
// Each wave owns 32 q-rows (2 q-sets of 16); K/V LDS fragments read once per tile
// feed both q-sets. 8 kv tiles of 64 keys per block; 3-slot counted-vmcnt ring.
__global__ __launch_bounds__(256, 3) void attn_split_kernel(
        const u16* __restrict__ Qp, const u16* __restrict__ Kp,
        const u16* __restrict__ VpT, u16* __restrict__ Opart,
        float* __restrict__ ml) {
    __shared__ u16 lKV[3][2][64 * 64];   // [slot][K=0/V=1] = 49152 B
    const int NT = 8;
    const int tid = threadIdx.x;
    const int lane = tid & 63, wv = tid >> 6;      // wv 0..3
    const int c16 = lane & 15, g = lane >> 4;
    const int bid = blockIdx.x;
    const int qblk = bid >> 8;            // 0..3, high bits (XCD slab grouping)
    const int low = bid & 255;
    const int h = low & 15, z = low >> 4;  // z 0..15
    const int b = z >> 2, sp = z & 3;
    const int kvbase = sp * 512;

    bf16x8 qf[2][2];
#pragma unroll
    for (int qs = 0; qs < 2; qs++) {
        int qrow = b * 512 + qblk * 128 + qs * 64 + wv * 16 + c16;
        qf[qs][0] = *(const bf16x8*)(Qp + (size_t)qrow * 1024 + h * 64 + g * 8);
        qf[qs][1] = *(const bf16x8*)(Qp + (size_t)qrow * 1024 + h * 64 + 32 + g * 8);
    }

    f32x4 acc[2][4] = {};
    float m_s[2] = {-1e30f, -1e30f}, l_s[2] = {0.f, 0.f};   // log2 domain

    const int r0 = tid >> 3, c0 = (tid & 7) ^ (r0 & 7);
    const int r1 = 32 + r0,  c1 = (tid & 7) ^ (r1 & 7);
    const int dst0 = wv * 512, dst1 = 2048 + wv * 512;   // u16 offsets

    auto stageKV = [&](int t) {
        int slot = t % 3;
        int kv0 = kvbase + t * 64;
        u16* dK = &lKV[slot][0][0];
        u16* dV = &lKV[slot][1][0];
        gll16(Kp + (size_t)(b * 2048 + kv0 + r0) * 1024 + h * 64 + c0 * 8, dK + dst0);
        gll16(Kp + (size_t)(b * 2048 + kv0 + r1) * 1024 + h * 64 + c1 * 8, dK + dst1);
        gll16(VpT + (size_t)(h * 64 + r0) * 8192 + b * 2048 + kv0 + c0 * 8, dV + dst0);
        gll16(VpT + (size_t)(h * 64 + r1) * 8192 + b * 2048 + kv0 + c1 * 8, dV + dst1);
    };

    stageKV(0); stageKV(1);
    for (int t = 0; t < NT; ++t) {
        if (t < NT - 1) { WAITV4(); } else { WAITV0(); }
        BAR();
        if (t + 2 < NT) stageKV(t + 2);

        const int slot = t % 3;
        const u16* lK = &lKV[slot][0][0];
        const u16* lV = &lKV[slot][1][0];

        // S^T = K Q^T for both q-sets; K fragments read once
        f32x4 s[2][4];
#pragma unroll
        for (int n = 0; n < 4; n++) {
            s[0][n] = f32x4{0.f, 0.f, 0.f, 0.f};
            s[1][n] = f32x4{0.f, 0.f, 0.f, 0.f};
        }
#pragma unroll
        for (int n = 0; n < 4; n++) {
            int key = n * 16 + c16;
#pragma unroll
            for (int kk = 0; kk < 2; kk++) {
                bf16x8 kf = *(const bf16x8*)&lK[key * 64 + (((kk * 4 + g) ^ (key & 7))) * 8];
                s[0][n] = mfma16(kf, qf[0][kk], s[0][n]);
                s[1][n] = mfma16(kf, qf[1][kk], s[1][n]);
            }
        }

        // per-q-set online softmax (q = c16), in-register + 2 shuffles each
        uint32_t r[2][4][2];
#pragma unroll
        for (int qs = 0; qs < 2; qs++) {
            float mn0 = fmaxf(fmaxf(s[qs][0][0], s[qs][0][1]), fmaxf(s[qs][0][2], s[qs][0][3]));
            float mn1 = fmaxf(fmaxf(s[qs][1][0], s[qs][1][1]), fmaxf(s[qs][1][2], s[qs][1][3]));
            float mn2 = fmaxf(fmaxf(s[qs][2][0], s[qs][2][1]), fmaxf(s[qs][2][2], s[qs][2][3]));
            float mn3 = fmaxf(fmaxf(s[qs][3][0], s[qs][3][1]), fmaxf(s[qs][3][2], s[qs][3][3]));
            float mx = fmaxf(fmaxf(mn0, mn1), fmaxf(mn2, mn3));
            mx = fmaxf(mx, __shfl_xor(mx, 16));
            mx = fmaxf(mx, __shfl_xor(mx, 32));

            if (!__all(mx - m_s[qs] <= 8.0f)) {
                float mn = fmaxf(m_s[qs], mx);
                float al = exp2f(m_s[qs] - mn);
                m_s[qs] = mn;
                l_s[qs] *= al;
                float alr[4];
#pragma unroll
                for (int j = 0; j < 4; j++) alr[j] = __shfl(al, g * 4 + j);
#pragma unroll
                for (int nd = 0; nd < 4; nd++)
#pragma unroll
                    for (int j = 0; j < 4; j++) acc[qs][nd][j] *= alr[j];
            }

            float sums[4];
#pragma unroll
            for (int n = 0; n < 4; n++) {
                float p0 = exp2f(s[qs][n][0] - m_s[qs]);
                float p1 = exp2f(s[qs][n][1] - m_s[qs]);
                float p2 = exp2f(s[qs][n][2] - m_s[qs]);
                float p3 = exp2f(s[qs][n][3] - m_s[qs]);
                sums[n] = (p0 + p1) + (p2 + p3);
                union { bf16x2 h; uint32_t u; } ca, cb;
                ca.h[0] = (__bf16)p0; ca.h[1] = (__bf16)p1;
                cb.h[0] = (__bf16)p2; cb.h[1] = (__bf16)p3;
                r[qs][n][0] = ca.u; r[qs][n][1] = cb.u;
            }
            float sum = (sums[0] + sums[1]) + (sums[2] + sums[3]);
            sum += __shfl_xor(sum, 16);
            sum += __shfl_xor(sum, 32);
            l_s[qs] += sum;
        }

        // O += P @ V for both q-sets; V fragments read once
#pragma unroll
        for (int kk2 = 0; kk2 < 2; kk2++) {
            union { bf16x8 v8; uint32_t u[4]; } pa0, pa1;
            pa0.u[0] = r[0][kk2 * 2][0];     pa0.u[1] = r[0][kk2 * 2][1];
            pa0.u[2] = r[0][kk2 * 2 + 1][0]; pa0.u[3] = r[0][kk2 * 2 + 1][1];
            pa1.u[0] = r[1][kk2 * 2][0];     pa1.u[1] = r[1][kk2 * 2][1];
            pa1.u[2] = r[1][kk2 * 2 + 1][0]; pa1.u[3] = r[1][kk2 * 2 + 1][1];
#pragma unroll
            for (int nd = 0; nd < 4; nd++) {
                int d = nd * 16 + c16;
                bf16x8 vf = *(const bf16x8*)&lV[d * 64 + (((kk2 * 4 + g) ^ (d & 7))) * 8];
                acc[0][nd] = mfma16(pa0.v8, vf, acc[0][nd]);
                acc[1][nd] = mfma16(pa1.v8, vf, acc[1][nd]);
            }
        }
    }

    // write partials: unnormalized O in bf16 + per-row m,l (g==0 lanes)
#pragma unroll
    for (int qs = 0; qs < 2; qs++) {
#pragma unroll
        for (int j = 0; j < 4; j++) {
            int rowq = b * 512 + qblk * 128 + qs * 64 + wv * 16 + g * 4 + j;
            size_t idx = (size_t)sp * 32768 + (size_t)rowq * 16 + h;
#pragma unroll
            for (int nd = 0; nd < 4; nd++)
                Opart[idx * 64 + nd * 16 + c16] = f2bf(acc[qs][nd][j]);
        }
        if (g == 0) {
            int rowq = b * 512 + qblk * 128 + qs * 64 + wv * 16 + c16;
            size_t idx = (size_t)sp * 32768 + (size_t)rowq * 16 + h;
            ml[idx * 2] = m_s[qs];
            ml[idx * 2 + 1] = l_s[qs];
        }
    }
}

// ---------------- combine the 4 kv-split partials -> X bf16 (log2-domain m) ------
__global__ __launch_bounds__(256) void attn_combine_kernel(
        const u16* __restrict__ Opart, const float* __restrict__ ml,
        u16* __restrict__ X) {
    const int tid = threadIdx.x;
    const int r = blockIdx.x * 4 + (tid >> 6);   // rowhead 0..32767
    const int d = tid & 63;
    float m[4], l[4];
#pragma unroll
    for (int i = 0; i < 4; i++) {
        m[i] = ml[((size_t)i * 32768 + r) * 2];
        l[i] = ml[((size_t)i * 32768 + r) * 2 + 1];
    }
    float M = fmaxf(fmaxf(m[0], m[1]), fmaxf(m[2], m[3]));
    float den = 0.f, num = 0.f;
#pragma unroll
    for (int i = 0; i < 4; i++) {
        float a = exp2f(m[i] - M);
        den += l[i] * a;
        num += bf2f(Opart[((size_t)i * 32768 + r) * 64 + d]) * a;
    }
    float o = num / den;
    int qrow = r >> 4, h = r & 15;
    X[(size_t)qrow * 1024 + h * 64 + d] = f2bf(o);
}

// ---------------- launch ----------------
extern "C" void kernel_launch(void* const* d_in, const int* in_sizes, int n_in,
                              void* d_out, int out_size, void* d_ws, size_t ws_size,
                              hipStream_t stream) {
    const float* queries = (const float*)d_in[0];   // [4,512,1024]
    const float* context = (const float*)d_in[1];   // [4,2048,1024]
    const float* Wq      = (const float*)d_in[2];   // [1024,1024]
    const float* bq      = (const float*)d_in[3];   // [1024]
    const float* Wkv     = (const float*)d_in[4];   // [1024,2048]
    const float* bkv     = (const float*)d_in[5];   // [2048]
    const float* Wo      = (const float*)d_in[6];   // [1024,1024]
    const float* bo      = (const float*)d_in[7];   // [1024]

    char* ws = (char*)d_ws;
    u16* qb   = (u16*)(ws);                         // queries bf16   4MB (dead after Q-proj)
    u16* cb   = (u16*)(ws + (4ull  << 20));         // context bf16  16MB (dead after KV GEMM)
    u16* WqT  = (u16*)(ws + (20ull << 20));         // Wq^T bf16      2MB
    u16* WkvT = (u16*)(ws + (22ull << 20));         // Wkv^T bf16     4MB
    u16* WoT  = (u16*)(ws + (26ull << 20));         // Wo^T bf16      2MB
    u16* Qp   = (u16*)(ws + (28ull << 20));         // q proj (x0.125*log2e) 4MB
    u16* Kp   = (u16*)(ws + (32ull << 20));         // k proj        16MB
    u16* VpT  = (u16*)(ws + (48ull << 20));         // v proj ^T (vslot cols) 16MB
    u16* X    = (u16*)(ws + (64ull << 20));         // attn out       4MB
    float* ml    = (float*)qb;                      // 1MB, aliases dead qb
    u16*   Opart = (u16*)cb;                        // 16MB bf16 (4 splits), aliases cb

    prep_kernel<<<dim3(14336), dim3(256), 0, stream>>>(queries, context, Wq, Wkv, Wo,
                                                       qb, cb, WqT, WkvT, WoT);

    // scale = 1/8 * log2(e): scores computed directly in exp2 domain
    gemm_bt<0><<<dim3(8, 16), dim3(512), 0, stream>>>(qb, WqT, bq, 2048, 1024, 1024,
                                                      0.18033688f, (void*)Qp);
    gemm_kv_ring<<<dim3(8, 32), dim3(512), 0, stream>>>(cb, WkvT, bkv, Kp, VpT);
    attn_split_kernel<<<dim3(1024), dim3(256), 0, stream>>>(Qp, Kp, VpT, Opart, ml);
    attn_combine_kernel<<<dim3(8192), dim3(256), 0, stream>>>(Opart, ml, X);
    gemm_bt<2><<<dim3(8, 16), dim3(512), 0, stream>>>(X, WoT, bo, 2048, 1024, 1024,
                                                      1.0f, d_out);
}

// Round 12
// 120.107 us; speedup vs baseline: 1.4904x; 1.0335x over previous
//
#include <hip/hip_runtime.h>
#include <hip/hip_bf16.h>
#include <stdint.h>

typedef unsigned short u16;
typedef __attribute__((ext_vector_type(8))) __bf16 bf16x8;
typedef __attribute__((ext_vector_type(2))) __bf16 bf16x2;
typedef __attribute__((ext_vector_type(4))) float f32x4;
typedef __attribute__((ext_vector_type(4))) u16 u16x4;
typedef __attribute__((ext_vector_type(4))) float f32x4v;

typedef __attribute__((address_space(1))) void gvoid_t;
typedef __attribute__((address_space(3))) void lvoid_t;

#define BAR()    asm volatile("s_barrier" ::: "memory")
#define WAITV0() asm volatile("s_waitcnt vmcnt(0)" ::: "memory")
#define WAITV2() asm volatile("s_waitcnt vmcnt(2)" ::: "memory")
#define WAITV4() asm volatile("s_waitcnt vmcnt(4)" ::: "memory")
#define WAITV8() asm volatile("s_waitcnt vmcnt(8)" ::: "memory")

__device__ inline u16 f2bf(float f) {
    uint32_t u = __float_as_uint(f);
    u += 0x7fff + ((u >> 16) & 1);   // RNE
    return (u16)(u >> 16);
}

__device__ inline float bf2f(u16 v) {
    return __uint_as_float(((uint32_t)v) << 16);
}

__device__ inline void gll16(const void* g, void* l) {
    __builtin_amdgcn_global_load_lds((gvoid_t*)g, (lvoid_t*)l, 16, 0, 0);
}

__device__ inline f32x4 mfma16(bf16x8 a, bf16x8 b, f32x4 c) {
    return __builtin_amdgcn_mfma_f32_16x16x32_bf16(a, b, c, 0, 0, 0);
}

// V slot permutation: context row r (mod 64) -> storage slot, so that the PV
// A-fragment is IN-LANE after swapped QK^T (keys n*16+g*4+j live in lane g).
__device__ inline int vslot(int r) {
    int n = r >> 4;
    return ((n >> 1) << 5) + (((r >> 2) & 3) << 3) + ((n & 1) << 2) + (r & 3);
}

// ---------------- fused prep: casts (blocks 0..10239) + transposes (10240..14335)
__global__ __launch_bounds__(256) void prep_kernel(
        const float* __restrict__ q, const float* __restrict__ c,
        const float* __restrict__ Wq, const float* __restrict__ Wkv,
        const float* __restrict__ Wo, u16* __restrict__ qb,
        u16* __restrict__ cb, u16* __restrict__ WqT,
        u16* __restrict__ WkvT, u16* __restrict__ WoT) {
    const int bid = blockIdx.x;
    const int tid = threadIdx.x;
    if (bid < 10240) {
        int i = bid * 256 + tid;
        const float* src; u16* dst; int j;
        if (i < 524288) { src = q; dst = qb; j = i; }
        else            { src = c; dst = cb; j = i - 524288; }
        f32x4v f = ((const f32x4v*)src)[j];
        u16x4 o;
        o[0] = f2bf(f[0]); o[1] = f2bf(f[1]); o[2] = f2bf(f[2]); o[3] = f2bf(f[3]);
        ((u16x4*)dst)[j] = o;
        return;
    }
    int b2 = bid - 10240;
    const float* W; u16* WT; int N, n0, k0;
    if (b2 < 1024)      { W = Wq;  WT = WqT;  N = 1024; n0 = (b2 & 31) * 32; k0 = (b2 >> 5) * 32; }
    else if (b2 < 3072) { int b3 = b2 - 1024; W = Wkv; WT = WkvT; N = 2048; n0 = (b3 & 63) * 32; k0 = (b3 >> 6) * 32; }
    else                { int b3 = b2 - 3072; W = Wo;  WT = WoT;  N = 1024; n0 = (b3 & 31) * 32; k0 = (b3 >> 5) * 32; }
    __shared__ float t[32][33];
    int x = tid & 31, y = tid >> 5;
    for (int yy = y; yy < 32; yy += 8)
        t[yy][x] = W[(size_t)(k0 + yy) * N + n0 + x];
    __syncthreads();
    for (int yy = y; yy < 32; yy += 8)
        WT[(size_t)(n0 + yy) * 1024 + k0 + x] = f2bf(t[x][yy]);
}

// ---------------- small GEMM: 64x128 tile, 8 waves, 4-slot counted ring ---------
// Grid (N/128, M/64) = 256 blocks -> every CU active (was 128 blocks = half chip).
// A-tile = 256 chunks (4 waves' worth): waves 4-7 DUPLICATE waves 0-3's A chunks
// (same source -> identical LDS bytes, benign) so every thread issues exactly
// 2 gll16/tile and the proven vmcnt(4/2/0) counted-ring accounting is unchanged.
// MODE 0: out0 = bf16[M][N], value=(acc+bias)*scale     (Q proj)
// MODE 2: out0 = fp32 [M][N]                            (O proj -> d_out)
template <int MODE>
__global__ __launch_bounds__(512, 2) void gemm_bt(
        const u16* __restrict__ A, const u16* __restrict__ Bt,
        const float* __restrict__ bias, int M, int N, int K,
        float scale, void* __restrict__ out0) {
    __shared__ u16 lds[4][6144];          // [slot][A: 64*32 | B at +2048: 128*32]
    const int NT = K >> 5;                // K/32
    const int tid = threadIdx.x;          // 0..511
    const int lane = tid & 63, wv = tid >> 6;   // wv 0..7
    const int c16 = lane & 15, g = lane >> 4;
    const int m0 = blockIdx.y * 64, n0 = blockIdx.x * 128;

    // A chunk (waves 0-3 real, 4-7 duplicate): idxA = (wv&3)*64 + lane
    const int idxA = (wv & 3) * 64 + lane;
    const int rA = idxA >> 2, ccA = (idxA & 3) ^ ((rA >> 1) & 3);
    const size_t offA = (size_t)(m0 + rA) * K + ccA * 8;
    const int dstA = (wv & 3) * 512;      // u16, wave-uniform (lane*16B by HW)
    // B chunk: idxB = wv*64 + lane (512 chunks, rows 0..127)
    const int idxB = wv * 64 + lane;
    const int rB = idxB >> 2, ccB = (idxB & 3) ^ ((rB >> 1) & 3);
    const size_t offB = (size_t)(n0 + rB) * K + ccB * 8;
    const int dstB = 2048 + wv * 512;     // u16

    auto stage = [&](int t) {
        gll16(A + offA + t * 32, &lds[t & 3][dstA]);
        gll16(Bt + offB + t * 32, &lds[t & 3][dstB]);
    };

    // per-wave output: rows (wv>>1)*16 .. +15, cols (wv&1)*64 .. +63
    const int wm = (wv >> 1) * 16, wn = (wv & 1) * 64;
    f32x4 acc[4] = {};

    auto compute = [&](int slot) {
        const u16* la = &lds[slot][0];
        const u16* lb = &lds[slot][2048];
        int rowa = wm + c16;
        bf16x8 af = *(const bf16x8*)&la[rowa * 32 + (g ^ ((rowa >> 1) & 3)) * 8];
        bf16x8 bfr[4];
#pragma unroll
        for (int n = 0; n < 4; n++) {
            int row = wn + n * 16 + c16;
            bfr[n] = *(const bf16x8*)&lb[row * 32 + (g ^ ((row >> 1) & 3)) * 8];
        }
#pragma unroll
        for (int n = 0; n < 4; n++)
            acc[n] = mfma16(af, bfr[n], acc[n]);
    };

    stage(0); stage(1); stage(2);        // 6 loads/thread in flight

    for (int t = 0; t < NT - 2; ++t) {
        WAITV4();
        BAR();
        if (t + 3 < NT) stage(t + 3);
        compute(t & 3);
    }
    WAITV2(); BAR(); compute((NT - 2) & 3);
    WAITV0(); BAR(); compute((NT - 1) & 3);

#pragma unroll
    for (int n = 0; n < 4; n++) {
        int col = n0 + wn + n * 16 + c16;
        float bv = bias[col];
        int rowb = m0 + wm + g * 4;
#pragma unroll
        for (int j = 0; j < 4; j++) {
            float v = (acc[n][j] + bv) * scale;
            int row = rowb + j;
            if (MODE == 0) {
                ((u16*)out0)[(size_t)row * N + col] = f2bf(v);
            } else {
                ((float*)out0)[(size_t)row * N + col] = v;
            }
        }
    }
}

// ---------------- big GEMM: 256x256 tile, 8 waves, 4-deep ring, counted vmcnt ----
// (R6-proven version; 44 us, 0 conflicts)
__global__ __launch_bounds__(512, 2) void gemm_kv_ring(
        const u16* __restrict__ A, const u16* __restrict__ Bt,
        const float* __restrict__ bias, u16* __restrict__ Kp,
        u16* __restrict__ VpT) {
    __shared__ u16 lds[4][2][256 * 32];   // [slot][A=0/B=1][row*32 + swz-chunk*8]
    const int K = 1024, NT = 32;          // K / 32
    const int tid = threadIdx.x;
    const int lane = tid & 63, wv = tid >> 6;
    const int c16 = lane & 15, g = lane >> 4;

    const int nwg = gridDim.x * gridDim.y;
    const int bid = blockIdx.y * gridDim.x + blockIdx.x;
    const int cpx = nwg >> 3;
    const int sw = (bid & 7) * cpx + (bid >> 3);
    const int bx = sw % gridDim.x, by = sw / gridDim.x;
    const int m0 = by * 256, n0 = bx * 256;

    const int isB = wv >> 2;
    const int rbase = (wv & 3) * 64;
    const u16* src = isB ? Bt : A;
    const int base0 = isB ? n0 : m0;
    size_t off[4];
    const u16* ldst[4];
#pragma unroll
    for (int i = 0; i < 4; i++) {
        int rl = rbase + i * 16 + (lane >> 2);
        int ch = (lane & 3) ^ ((rl >> 1) & 3);
        off[i] = (size_t)(base0 + rl) * K + ch * 8;
        ldst[i] = &lds[0][0][0] + ((size_t)isB * 256 * 32) + (size_t)(rbase + i * 16) * 32;
    }
    const size_t slotStride = 2 * 256 * 32;

    auto stage = [&](int t) {
        const u16* s0 = src + (size_t)t * 32;
        u16* d = (u16*)ldst[0] + (size_t)(t & 3) * slotStride;
        gll16(s0 + off[0], d);
        gll16(s0 + off[1], d + 16 * 32);
        gll16(s0 + off[2], d + 32 * 32);
        gll16(s0 + off[3], d + 48 * 32);
    };

    const int wm = wv >> 2;
    const int wn = wv & 3;
    f32x4 acc[8][4] = {};

    auto compute = [&](int slot) {
        const u16* la = &lds[slot][0][0];
        const u16* lb = &lds[slot][1][0];
        bf16x8 af[8], bfr[4];
#pragma unroll
        for (int m = 0; m < 8; m++) {
            int row = wm * 128 + m * 16 + c16;
            af[m] = *(const bf16x8*)&la[row * 32 + (g ^ ((row >> 1) & 3)) * 8];
        }
#pragma unroll
        for (int n = 0; n < 4; n++) {
            int row = wn * 64 + n * 16 + c16;
            bfr[n] = *(const bf16x8*)&lb[row * 32 + (g ^ ((row >> 1) & 3)) * 8];
        }
#pragma unroll
        for (int m = 0; m < 8; m++)
#pragma unroll
            for (int n = 0; n < 4; n++)
                acc[m][n] = mfma16(af[m], bfr[n], acc[m][n]);
    };

    stage(0); stage(1); stage(2);

    for (int t = 0; t < NT - 2; ++t) {
        WAITV8();
        BAR();
        if (t + 3 < NT) stage(t + 3);
        compute(t & 3);
    }
    WAITV4(); BAR(); compute((NT - 2) & 3);
    WAITV0(); BAR(); compute((NT - 1) & 3);

    const bool isV = (n0 >= 1024);
#pragma unroll
    for (int n = 0; n < 4; n++) {
        int col = n0 + wn * 64 + n * 16 + c16;
        float bv = bias[col];
#pragma unroll
        for (int m = 0; m < 8; m++) {
            int rowb = m0 + wm * 128 + m * 16 + g * 4;
            if (isV) {
                u16x4 pk;
#pragma unroll
                for (int j = 0; j < 4; j++) pk[j] = f2bf(acc[m][n][j] + bv);
                int vcol = (rowb & ~63) + vslot(rowb & 63);
                *(u16x4*)&VpT[(size_t)(col - 1024) * 8192 + vcol] = pk;
            } else {
#pragma unroll
                for (int j = 0; j < 4; j++)
                    Kp[(size_t)(rowb + j) * 1024 + col] = f2bf(acc[m][n][j] + bv);
            }
        }
    }
}

// ---------------- flash attention: QBLK=128, 4 waves x 2 q-sets, kv-split x4 ----
__global__ __launch_bounds__(256, 3) void attn_split_kernel(
        const u16* __restrict__ Qp, const u16* __restrict__ Kp,
        const u16* __restrict__ VpT, u16* __restrict__ Opart,
        float* __restrict__ ml) {
    __shared__ u16 lKV[3][2][64 * 64];   // [slot][K=0/V=1] = 49152 B
    const int NT = 8;
    const int tid = threadIdx.x;
    const int lane = tid & 63, wv = tid >> 6;      // wv 0..3
    const int c16 = lane & 15, g = lane >> 4;
    const int bid = blockIdx.x;
    const int qblk = bid >> 8;            // 0..3, high bits (XCD slab grouping)
    const int low = bid & 255;
    const int h = low & 15, z = low >> 4;  // z 0..15
    const int b = z >> 2, sp = z & 3;
    const int kvbase = sp * 512;

    bf16x8 qf[2][2];
#pragma unroll
    for (int qs = 0; qs < 2; qs++) {
        int qrow = b * 512 + qblk * 128 + qs * 64 + wv * 16 + c16;
        qf[qs][0] = *(const bf16x8*)(Qp + (size_t)qrow * 1024 + h * 64 + g * 8);
        qf[qs][1] = *(const bf16x8*)(Qp + (size_t)qrow * 1024 + h * 64 + 32 + g * 8);
    }

    f32x4 acc[2][4] = {};
    float m_s[2] = {-1e30f, -1e30f}, l_s[2] = {0.f, 0.f};   // log2 domain

    const int r0 = tid >> 3, c0 = (tid & 7) ^ (r0 & 7);
    const int r1 = 32 + r0,  c1 = (tid & 7) ^ (r1 & 7);
    const int dst0 = wv * 512, dst1 = 2048 + wv * 512;   // u16 offsets

    auto stageKV = [&](int t) {
        int slot = t % 3;
        int kv0 = kvbase + t * 64;
        u16* dK = &lKV[slot][0][0];
        u16* dV = &lKV[slot][1][0];
        gll16(Kp + (size_t)(b * 2048 + kv0 + r0) * 1024 + h * 64 + c0 * 8, dK + dst0);
        gll16(Kp + (size_t)(b * 2048 + kv0 + r1) * 1024 + h * 64 + c1 * 8, dK + dst1);
        gll16(VpT + (size_t)(h * 64 + r0) * 8192 + b * 2048 + kv0 + c0 * 8, dV + dst0);
        gll16(VpT + (size_t)(h * 64 + r1) * 8192 + b * 2048 + kv0 + c1 * 8, dV + dst1);
    };

    stageKV(0); stageKV(1);
    for (int t = 0; t < NT; ++t) {
        if (t < NT - 1) { WAITV4(); } else { WAITV0(); }
        BAR();
        if (t + 2 < NT) stageKV(t + 2);

        const int slot = t % 3;
        const u16* lK = &lKV[slot][0][0];
        const u16* lV = &lKV[slot][1][0];

        f32x4 s[2][4];
#pragma unroll
        for (int n = 0; n < 4; n++) {
            s[0][n] = f32x4{0.f, 0.f, 0.f, 0.f};
            s[1][n] = f32x4{0.f, 0.f, 0.f, 0.f};
        }
#pragma unroll
        for (int n = 0; n < 4; n++) {
            int key = n * 16 + c16;
#pragma unroll
            for (int kk = 0; kk < 2; kk++) {
                bf16x8 kf = *(const bf16x8*)&lK[key * 64 + (((kk * 4 + g) ^ (key & 7))) * 8];
                s[0][n] = mfma16(kf, qf[0][kk], s[0][n]);
                s[1][n] = mfma16(kf, qf[1][kk], s[1][n]);
            }
        }

        uint32_t r[2][4][2];
#pragma unroll
        for (int qs = 0; qs < 2; qs++) {
            float mn0 = fmaxf(fmaxf(s[qs][0][0], s[qs][0][1]), fmaxf(s[qs][0][2], s[qs][0][3]));
            float mn1 = fmaxf(fmaxf(s[qs][1][0], s[qs][1][1]), fmaxf(s[qs][1][2], s[qs][1][3]));
            float mn2 = fmaxf(fmaxf(s[qs][2][0], s[qs][2][1]), fmaxf(s[qs][2][2], s[qs][2][3]));
            float mn3 = fmaxf(fmaxf(s[qs][3][0], s[qs][3][1]), fmaxf(s[qs][3][2], s[qs][3][3]));
            float mx = fmaxf(fmaxf(mn0, mn1), fmaxf(mn2, mn3));
            mx = fmaxf(mx, __shfl_xor(mx, 16));
            mx = fmaxf(mx, __shfl_xor(mx, 32));

            if (!__all(mx - m_s[qs] <= 8.0f)) {
                float mn = fmaxf(m_s[qs], mx);
                float al = exp2f(m_s[qs] - mn);
                m_s[qs] = mn;
                l_s[qs] *= al;
                float alr[4];
#pragma unroll
                for (int j = 0; j < 4; j++) alr[j] = __shfl(al, g * 4 + j);
#pragma unroll
                for (int nd = 0; nd < 4; nd++)
#pragma unroll
                    for (int j = 0; j < 4; j++) acc[qs][nd][j] *= alr[j];
            }

            float sums[4];
#pragma unroll
            for (int n = 0; n < 4; n++) {
                float p0 = exp2f(s[qs][n][0] - m_s[qs]);
                float p1 = exp2f(s[qs][n][1] - m_s[qs]);
                float p2 = exp2f(s[qs][n][2] - m_s[qs]);
                float p3 = exp2f(s[qs][n][3] - m_s[qs]);
                sums[n] = (p0 + p1) + (p2 + p3);
                union { bf16x2 h; uint32_t u; } ca, cb;
                ca.h[0] = (__bf16)p0; ca.h[1] = (__bf16)p1;
                cb.h[0] = (__bf16)p2; cb.h[1] = (__bf16)p3;
                r[qs][n][0] = ca.u; r[qs][n][1] = cb.u;
            }
            float sum = (sums[0] + sums[1]) + (sums[2] + sums[3]);
            sum += __shfl_xor(sum, 16);
            sum += __shfl_xor(sum, 32);
            l_s[qs] += sum;
        }

#pragma unroll
        for (int kk2 = 0; kk2 < 2; kk2++) {
            union { bf16x8 v8; uint32_t u[4]; } pa0, pa1;
            pa0.u[0] = r[0][kk2 * 2][0];     pa0.u[1] = r[0][kk2 * 2][1];
            pa0.u[2] = r[0][kk2 * 2 + 1][0]; pa0.u[3] = r[0][kk2 * 2 + 1][1];
            pa1.u[0] = r[1][kk2 * 2][0];     pa1.u[1] = r[1][kk2 * 2][1];
            pa1.u[2] = r[1][kk2 * 2 + 1][0]; pa1.u[3] = r[1][kk2 * 2 + 1][1];
#pragma unroll
            for (int nd = 0; nd < 4; nd++) {
                int d = nd * 16 + c16;
                bf16x8 vf = *(const bf16x8*)&lV[d * 64 + (((kk2 * 4 + g) ^ (d & 7))) * 8];
                acc[0][nd] = mfma16(pa0.v8, vf, acc[0][nd]);
                acc[1][nd] = mfma16(pa1.v8, vf, acc[1][nd]);
            }
        }
    }

#pragma unroll
    for (int qs = 0; qs < 2; qs++) {
#pragma unroll
        for (int j = 0; j < 4; j++) {
            int rowq = b * 512 + qblk * 128 + qs * 64 + wv * 16 + g * 4 + j;
            size_t idx = (size_t)sp * 32768 + (size_t)rowq * 16 + h;
#pragma unroll
            for (int nd = 0; nd < 4; nd++)
                Opart[idx * 64 + nd * 16 + c16] = f2bf(acc[qs][nd][j]);
        }
        if (g == 0) {
            int rowq = b * 512 + qblk * 128 + qs * 64 + wv * 16 + c16;
            size_t idx = (size_t)sp * 32768 + (size_t)rowq * 16 + h;
            ml[idx * 2] = m_s[qs];
            ml[idx * 2 + 1] = l_s[qs];
        }
    }
}

// ---------------- combine the 4 kv-split partials -> X bf16 (log2-domain m) ------
__global__ __launch_bounds__(256) void attn_combine_kernel(
        const u16* __restrict__ Opart, const float* __restrict__ ml,
        u16* __restrict__ X) {
    const int tid = threadIdx.x;
    const int r = blockIdx.x * 4 + (tid >> 6);   // rowhead 0..32767
    const int d = tid & 63;
    float m[4], l[4];
#pragma unroll
    for (int i = 0; i < 4; i++) {
        m[i] = ml[((size_t)i * 32768 + r) * 2];
        l[i] = ml[((size_t)i * 32768 + r) * 2 + 1];
    }
    float M = fmaxf(fmaxf(m[0], m[1]), fmaxf(m[2], m[3]));
    float den = 0.f, num = 0.f;
#pragma unroll
    for (int i = 0; i < 4; i++) {
        float a = exp2f(m[i] - M);
        den += l[i] * a;
        num += bf2f(Opart[((size_t)i * 32768 + r) * 64 + d]) * a;
    }
    float o = num / den;
    int qrow = r >> 4, h = r & 15;
    X[(size_t)qrow * 1024 + h * 64 + d] = f2bf(o);
}

// ---------------- launch ----------------
extern "C" void kernel_launch(void* const* d_in, const int* in_sizes, int n_in,
                              void* d_out, int out_size, void* d_ws, size_t ws_size,
                              hipStream_t stream) {
    const float* queries = (const float*)d_in[0];   // [4,512,1024]
    const float* context = (const float*)d_in[1];   // [4,2048,1024]
    const float* Wq      = (const float*)d_in[2];   // [1024,1024]
    const float* bq      = (const float*)d_in[3];   // [1024]
    const float* Wkv     = (const float*)d_in[4];   // [1024,2048]
    const float* bkv     = (const float*)d_in[5];   // [2048]
    const float* Wo      = (const float*)d_in[6];   // [1024,1024]
    const float* bo      = (const float*)d_in[7];   // [1024]

    char* ws = (char*)d_ws;
    u16* qb   = (u16*)(ws);                         // queries bf16   4MB (dead after Q-proj)
    u16* cb   = (u16*)(ws + (4ull  << 20));         // context bf16  16MB (dead after KV GEMM)
    u16* WqT  = (u16*)(ws + (20ull << 20));         // Wq^T bf16      2MB
    u16* WkvT = (u16*)(ws + (22ull << 20));         // Wkv^T bf16     4MB
    u16* WoT  = (u16*)(ws + (26ull << 20));         // Wo^T bf16      2MB
    u16* Qp   = (u16*)(ws + (28ull << 20));         // q proj (x0.125*log2e) 4MB
    u16* Kp   = (u16*)(ws + (32ull << 20));         // k proj        16MB
    u16* VpT  = (u16*)(ws + (48ull << 20));         // v proj ^T (vslot cols) 16MB
    u16* X    = (u16*)(ws + (64ull << 20));         // attn out       4MB
    float* ml    = (float*)qb;                      // 1MB, aliases dead qb
    u16*   Opart = (u16*)cb;                        // 16MB bf16 (4 splits), aliases cb

    prep_kernel<<<dim3(14336), dim3(256), 0, stream>>>(queries, context, Wq, Wkv, Wo,
                                                       qb, cb, WqT, WkvT, WoT);

    // scale = 1/8 * log2(e): scores computed directly in exp2 domain
    gemm_bt<0><<<dim3(8, 32), dim3(512), 0, stream>>>(qb, WqT, bq, 2048, 1024, 1024,
                                                      0.18033688f, (void*)Qp);
    gemm_kv_ring<<<dim3(8, 32), dim3(512), 0, stream>>>(cb, WkvT, bkv, Kp, VpT);
    attn_split_kernel<<<dim3(1024), dim3(256), 0, stream>>>(Qp, Kp, VpT, Opart, ml);
    attn_combine_kernel<<<dim3(8192), dim3(256), 0, stream>>>(Opart, ml, X);
    gemm_bt<2><<<dim3(8, 32), dim3(512), 0, stream>>>(X, WoT, bo, 2048, 1024, 1024,
                                                      1.0f, d_out);
}